// Round 1
// baseline (1079.771 us; speedup 1.0000x reference)
//
#include <hip/hip_runtime.h>
#include <math.h>

__device__ __forceinline__ float lrelu(float v) { return v > 0.f ? v : 0.2f * v; }

// ---------------- init: zero counters ----------------
__global__ void k_init(int* cntD, int* curD, int* cntS, int* curS, float* tacc, int n) {
  int i = blockIdx.x * blockDim.x + threadIdx.x;
  if (i < n) { cntD[i] = 0; curD[i] = 0; cntS[i] = 0; curS[i] = 0; }
  if (i < 64) tacc[i] = 0.f;
}

// ---------------- degree count ----------------
__global__ void k_count(const int* __restrict__ src, const int* __restrict__ dst, int E,
                        int* cntD, int* cntS) {
  int e = blockIdx.x * blockDim.x + threadIdx.x;
  if (e < E) {
    atomicAdd(&cntD[dst[e]], 1);
    atomicAdd(&cntS[src[e]], 1);
  }
}

// ---------------- exclusive scan over n counts (1 block) ----------------
__global__ __launch_bounds__(1024) void k_scan(const int* __restrict__ cnt, int* __restrict__ off, int n) {
  __shared__ int buf[1024];
  __shared__ int carry;
  int t = threadIdx.x;
  if (t == 0) carry = 0;
  __syncthreads();
  for (int base = 0; base < n; base += 1024) {
    int v = (base + t < n) ? cnt[base + t] : 0;
    buf[t] = v;
    __syncthreads();
    for (int o = 1; o < 1024; o <<= 1) {
      int xval = 0;
      if (t >= o) xval = buf[t - o];
      __syncthreads();
      if (t >= o) buf[t] += xval;
      __syncthreads();
    }
    if (base + t < n) off[base + t] = carry + buf[t] - v;
    __syncthreads();
    if (t == 1023) carry += buf[1023];
    __syncthreads();
  }
  if (t == 0) off[n] = carry;
}

// ---------------- fill CSR lists ----------------
__global__ void k_fill(const int* __restrict__ src, const int* __restrict__ dst, int E,
                       const int* __restrict__ offD, int* curD, int* lstD,
                       const int* __restrict__ offS, int* curS, int* lstS) {
  int e = blockIdx.x * blockDim.x + threadIdx.x;
  if (e < E) {
    int d = dst[e], s = src[e];
    int p = atomicAdd(&curD[d], 1);
    lstD[offD[d] + p] = s;
    int q = atomicAdd(&curS[s], 1);
    lstS[offS[s] + q] = d;
  }
}

// ---------------- time embedding: sum_e relu(t*w+b) per k ----------------
__global__ __launch_bounds__(256) void k_time_reduce(const float* __restrict__ et,
    const float* __restrict__ tW1, const float* __restrict__ tb1,
    float* __restrict__ tacc, int E) {
  int t = threadIdx.x;
  int k = t & 63;
  int g = t >> 6;  // 0..3
  float wk = tW1[k], bk = tb1[k];
  float acc = 0.f;
  for (int e = blockIdx.x * 4 + g; e < E; e += gridDim.x * 4) {
    float v = et[e] * wk + bk;
    acc += v > 0.f ? v : 0.f;
  }
  __shared__ float buf[256];
  buf[t] = acc;
  __syncthreads();
  if (t < 64) {
    float s = buf[t] + buf[t + 64] + buf[t + 128] + buf[t + 192];
    atomicAdd(&tacc[t], s);
  }
}

// ---------------- cvec = (mean @ tW2 + tb2) @ fW1[128:] + fb1 ----------------
__global__ __launch_bounds__(128) void k_time_combine(const float* __restrict__ tacc,
    const float* __restrict__ tW2, const float* __restrict__ tb2,
    const float* __restrict__ fW1, const float* __restrict__ fb1,
    float* __restrict__ cvec, int E) {
  __shared__ float tm[128];
  int t = threadIdx.x;
  float inv = 1.f / (float)E;
  float acc = tb2[t];
  for (int k = 0; k < 64; ++k) acc += (tacc[k] * inv) * tW2[k * 128 + t];
  tm[t] = acc;
  __syncthreads();
  float c = fb1[t];
  for (int k = 0; k < 128; ++k) c += tm[k] * fW1[(128 + k) * 128 + t];
  cvec[t] = c;
}

// ---------------- f32 tiled GEMM: C[M,N] = A[M,K] @ B[K,N] (+bias)(+relu) ----------------
__global__ __launch_bounds__(256) void gemm_f32(
    const float* __restrict__ A, const float* __restrict__ B,
    float* __restrict__ C, const float* __restrict__ bias,
    int M, int N, int K, int relu)
{
  __shared__ float As[16][68];
  __shared__ float Bs[16][68];
  int tid = threadIdx.x;
  int bm = blockIdx.x * 64;
  int bn = blockIdx.y * 64;
  int tx = tid & 15, ty = tid >> 4;
  int arow = tid >> 2, acol = (tid & 3) << 2;
  int brow = tid >> 4, bcol = (tid & 15) << 2;
  float acc[4][4] = {};
  bool aval = (bm + arow) < M;
  const float* Aptr = A + (size_t)(bm + arow) * K + acol;
  const float* Bptr = B + (size_t)brow * N + bn + bcol;
  for (int k0 = 0; k0 < K; k0 += 16) {
    float4 av = make_float4(0.f, 0.f, 0.f, 0.f);
    if (aval) av = *reinterpret_cast<const float4*>(Aptr + k0);
    float4 bv = *reinterpret_cast<const float4*>(Bptr + (size_t)k0 * N);
    As[acol + 0][arow] = av.x;
    As[acol + 1][arow] = av.y;
    As[acol + 2][arow] = av.z;
    As[acol + 3][arow] = av.w;
    *reinterpret_cast<float4*>(&Bs[brow][bcol]) = bv;
    __syncthreads();
#pragma unroll
    for (int kk = 0; kk < 16; ++kk) {
      float4 a = *reinterpret_cast<const float4*>(&As[kk][ty << 2]);
      float4 b = *reinterpret_cast<const float4*>(&Bs[kk][tx << 2]);
      acc[0][0] += a.x * b.x; acc[0][1] += a.x * b.y; acc[0][2] += a.x * b.z; acc[0][3] += a.x * b.w;
      acc[1][0] += a.y * b.x; acc[1][1] += a.y * b.y; acc[1][2] += a.y * b.z; acc[1][3] += a.y * b.w;
      acc[2][0] += a.z * b.x; acc[2][1] += a.z * b.y; acc[2][2] += a.z * b.z; acc[2][3] += a.z * b.w;
      acc[3][0] += a.w * b.x; acc[3][1] += a.w * b.y; acc[3][2] += a.w * b.z; acc[3][3] += a.w * b.w;
    }
    __syncthreads();
  }
  float4 bb = make_float4(0.f, 0.f, 0.f, 0.f);
  if (bias) bb = *reinterpret_cast<const float4*>(&bias[bn + (tx << 2)]);
#pragma unroll
  for (int i = 0; i < 4; ++i) {
    int gm = bm + (ty << 2) + i;
    if (gm < M) {
      float4 o;
      o.x = acc[i][0] + bb.x; o.y = acc[i][1] + bb.y;
      o.z = acc[i][2] + bb.z; o.w = acc[i][3] + bb.w;
      if (relu) {
        o.x = fmaxf(o.x, 0.f); o.y = fmaxf(o.y, 0.f);
        o.z = fmaxf(o.z, 0.f); o.w = fmaxf(o.w, 0.f);
      }
      *reinterpret_cast<float4*>(&C[(size_t)gm * N + bn + (tx << 2)]) = o;
    }
  }
}

// ---------------- per-node attention dots: al/ar (one wave per head) ----------------
__global__ __launch_bounds__(256) void k_alar(const float* __restrict__ xl,
    const float* __restrict__ asrc, const float* __restrict__ adst,
    float* __restrict__ al, float* __restrict__ ar) {
  int n = blockIdx.x;
  int t = threadIdx.x;
  int h = t >> 6, l = t & 63;
  const float* xr = xl + (size_t)n * 512 + h * 128;
  const float* as_ = asrc + h * 128;
  const float* ad_ = adst + h * 128;
  float a1 = xr[l] * as_[l] + xr[l + 64] * as_[l + 64];
  float a2 = xr[l] * ad_[l] + xr[l + 64] * ad_[l + 64];
#pragma unroll
  for (int o = 32; o; o >>= 1) { a1 += __shfl_down(a1, o); a2 += __shfl_down(a2, o); }
  if (l == 0) { al[n * 4 + h] = a1; ar[n * 4 + h] = a2; }
}

// ---------------- GAT aggregation per dst node ----------------
// mode 0: out = relu(agg512 + bias512)   (N x 512)
// mode 1: out = relu(mean_heads(agg512) + bias128)  (N x 128)
__global__ __launch_bounds__(256) void k_gat_agg(
    const float* __restrict__ xl, const float* __restrict__ al, const float* __restrict__ ar,
    const int* __restrict__ off, const int* __restrict__ lst,
    const float* __restrict__ bias, float* __restrict__ out, int mode)
{
  __shared__ float sm[256][4];
  __shared__ float ss[256][4];
  __shared__ float mxs[4], invs[4];
  __shared__ float tmp[512];
  int d = blockIdx.x;
  int t = threadIdx.x;
  int base = off[d];
  int deg = off[d + 1] - base;
  float ar0 = ar[4 * d + 0], ar1 = ar[4 * d + 1], ar2 = ar[4 * d + 2], ar3 = ar[4 * d + 3];

  // phase 1: online softmax (max, denom) per head; self-edge seeded on thread 0
  float m0 = -1e30f, m1 = -1e30f, m2 = -1e30f, m3 = -1e30f;
  float s0 = 0.f, s1 = 0.f, s2 = 0.f, s3 = 0.f;
  if (t == 0) {
    float4 av = *reinterpret_cast<const float4*>(&al[4 * d]);
    m0 = lrelu(av.x + ar0); s0 = 1.f;
    m1 = lrelu(av.y + ar1); s1 = 1.f;
    m2 = lrelu(av.z + ar2); s2 = 1.f;
    m3 = lrelu(av.w + ar3); s3 = 1.f;
  }
  for (int j = t; j < deg; j += 256) {
    int sid = lst[base + j];
    float4 av = *reinterpret_cast<const float4*>(&al[4 * sid]);
    float lg;
    lg = lrelu(av.x + ar0);
    if (lg > m0) { s0 = s0 * __expf(m0 - lg) + 1.f; m0 = lg; } else s0 += __expf(lg - m0);
    lg = lrelu(av.y + ar1);
    if (lg > m1) { s1 = s1 * __expf(m1 - lg) + 1.f; m1 = lg; } else s1 += __expf(lg - m1);
    lg = lrelu(av.z + ar2);
    if (lg > m2) { s2 = s2 * __expf(m2 - lg) + 1.f; m2 = lg; } else s2 += __expf(lg - m2);
    lg = lrelu(av.w + ar3);
    if (lg > m3) { s3 = s3 * __expf(m3 - lg) + 1.f; m3 = lg; } else s3 += __expf(lg - m3);
  }
  sm[t][0] = m0; ss[t][0] = s0;
  sm[t][1] = m1; ss[t][1] = s1;
  sm[t][2] = m2; ss[t][2] = s2;
  sm[t][3] = m3; ss[t][3] = s3;
  __syncthreads();
  for (int str = 128; str; str >>= 1) {
    if (t < str) {
#pragma unroll
      for (int h = 0; h < 4; ++h) {
        float ma = sm[t][h], sa = ss[t][h];
        float mb = sm[t + str][h], sb = ss[t + str][h];
        float M = fmaxf(ma, mb);
        ss[t][h] = sa * __expf(ma - M) + sb * __expf(mb - M);
        sm[t][h] = M;
      }
    }
    __syncthreads();
  }
  if (t < 4) { mxs[t] = sm[0][t]; invs[t] = 1.f / ss[0][t]; }
  __syncthreads();

  // phase 2: weighted gather
  int c0 = t, c1 = t + 256;
  int h0 = t >> 7, h1 = h0 + 2;
  float mh0 = mxs[h0], mh1 = mxs[h1];
  float i0 = invs[h0], i1 = invs[h1];
  float arh0 = ar[4 * d + h0], arh1 = ar[4 * d + h1];
  float acc0 = 0.f, acc1 = 0.f;
  for (int j = 0; j < deg; ++j) {
    int sid = lst[base + j];
    float a0 = __expf(lrelu(al[4 * sid + h0] + arh0) - mh0) * i0;
    float a1 = __expf(lrelu(al[4 * sid + h1] + arh1) - mh1) * i1;
    const float* xr = xl + (size_t)sid * 512;
    acc0 += a0 * xr[c0];
    acc1 += a1 * xr[c1];
  }
  {
    float a0 = __expf(lrelu(al[4 * d + h0] + arh0) - mh0) * i0;
    float a1 = __expf(lrelu(al[4 * d + h1] + arh1) - mh1) * i1;
    const float* xr = xl + (size_t)d * 512;
    acc0 += a0 * xr[c0];
    acc1 += a1 * xr[c1];
  }
  if (mode == 0) {
    out[(size_t)d * 512 + c0] = fmaxf(acc0 + bias[c0], 0.f);
    out[(size_t)d * 512 + c1] = fmaxf(acc1 + bias[c1], 0.f);
  } else {
    tmp[c0] = acc0; tmp[c1] = acc1;
    __syncthreads();
    if (t < 128) {
      float v = (tmp[t] + tmp[t + 128] + tmp[t + 256] + tmp[t + 384]) * 0.25f + bias[t];
      out[(size_t)d * 128 + t] = fmaxf(v, 0.f);
    }
  }
}

// ---------------- final src-side segment sum (incl. self loop) ----------------
__global__ __launch_bounds__(128) void k_aggsrc(const float* __restrict__ h3,
    const int* __restrict__ off, const int* __restrict__ lst, float* __restrict__ out) {
  int n = blockIdx.x, t = threadIdx.x;
  float acc = h3[(size_t)n * 128 + t];
  int b = off[n], e = off[n + 1];
  for (int j = b; j < e; ++j) acc += h3[(size_t)lst[j] * 128 + t];
  out[(size_t)n * 128 + t] = acc;
}

// ---------------- layernorm + residual (out holds x_res, overwritten) ----------------
__global__ __launch_bounds__(128) void k_ln_res(const float* __restrict__ z,
    const float* __restrict__ g, const float* __restrict__ bt, float* __restrict__ out) {
  int n = blockIdx.x, t = threadIdx.x;
  float v = z[(size_t)n * 128 + t];
  __shared__ float red[2];
  float s = v;
#pragma unroll
  for (int o = 32; o; o >>= 1) s += __shfl_down(s, o);
  if ((t & 63) == 0) red[t >> 6] = s;
  __syncthreads();
  float mu = (red[0] + red[1]) * (1.f / 128.f);
  float dv = v - mu;
  float q = dv * dv;
  __syncthreads();
#pragma unroll
  for (int o = 32; o; o >>= 1) q += __shfl_down(q, o);
  if ((t & 63) == 0) red[t >> 6] = q;
  __syncthreads();
  float var = (red[0] + red[1]) * (1.f / 128.f);
  float y = dv * rsqrtf(var + 1e-5f) * g[t] + bt[t];
  out[(size_t)n * 128 + t] = y + out[(size_t)n * 128 + t];
}

extern "C" void kernel_launch(void* const* d_in, const int* in_sizes, int n_in,
                              void* d_out, int out_size, void* d_ws, size_t ws_size,
                              hipStream_t stream) {
  (void)n_in; (void)out_size; (void)ws_size;
  const float* x   = (const float*)d_in[0];
  const float* et  = (const float*)d_in[1];
  const float* W1  = (const float*)d_in[2];
  const float* as1 = (const float*)d_in[3];
  const float* ad1 = (const float*)d_in[4];
  const float* b1  = (const float*)d_in[5];
  const float* W2  = (const float*)d_in[6];
  const float* as2 = (const float*)d_in[7];
  const float* ad2 = (const float*)d_in[8];
  const float* b2  = (const float*)d_in[9];
  const float* W3  = (const float*)d_in[10];
  const float* as3 = (const float*)d_in[11];
  const float* ad3 = (const float*)d_in[12];
  const float* b3  = (const float*)d_in[13];
  const float* tW1 = (const float*)d_in[14];
  const float* tb1 = (const float*)d_in[15];
  const float* tW2 = (const float*)d_in[16];
  const float* tb2 = (const float*)d_in[17];
  const float* fW1 = (const float*)d_in[18];
  const float* fb1 = (const float*)d_in[19];
  const float* fW2 = (const float*)d_in[20];
  const float* fb2 = (const float*)d_in[21];
  const float* lng = (const float*)d_in[22];
  const float* lnb = (const float*)d_in[23];
  const float* rW  = (const float*)d_in[24];
  const float* rb  = (const float*)d_in[25];
  const int*   ei  = (const int*)d_in[26];
  const int N = in_sizes[0] / 64;     // 20000
  const int E = in_sizes[26] / 2;     // 320000
  const int* src = ei;
  const int* dst = ei + E;

  char* cur = (char*)d_ws;
  auto carve = [&](size_t bytes) { char* p = cur; cur += (bytes + 255) & ~(size_t)255; return p; };
  float* bufA = (float*)carve((size_t)N * 512 * 4);
  float* bufB = (float*)carve((size_t)N * 512 * 4);
  float* al   = (float*)carve((size_t)N * 4 * 4);
  float* ar   = (float*)carve((size_t)N * 4 * 4);
  float* tacc = (float*)carve(64 * 4);
  float* cvec = (float*)carve(128 * 4);
  int* cntD = (int*)carve((size_t)N * 4);
  int* offD = (int*)carve((size_t)(N + 1) * 4);
  int* curD = (int*)carve((size_t)N * 4);
  int* lstD = (int*)carve((size_t)E * 4);
  int* cntS = (int*)carve((size_t)N * 4);
  int* offS = (int*)carve((size_t)(N + 1) * 4);
  int* curS = (int*)carve((size_t)N * 4);
  int* lstS = (int*)carve((size_t)E * 4);

  float* h3   = bufB;                       // N x 128, written after xl3 consumed
  float* aggv = bufB + (size_t)N * 128;     // N x 128
  float* z1   = bufA;                       // N x 128 (xl3 dead by then)
  float* z2   = bufA + (size_t)N * 128;     // N x 128
  float* xres = (float*)d_out;              // x_res parked in d_out

  // CSR build
  k_init<<<(N + 255) / 256, 256, 0, stream>>>(cntD, curD, cntS, curS, tacc, N);
  k_count<<<(E + 255) / 256, 256, 0, stream>>>(src, dst, E, cntD, cntS);
  k_scan<<<1, 1024, 0, stream>>>(cntD, offD, N);
  k_scan<<<1, 1024, 0, stream>>>(cntS, offS, N);
  k_fill<<<(E + 255) / 256, 256, 0, stream>>>(src, dst, E, offD, curD, lstD, offS, curS, lstS);

  // time path -> cvec
  k_time_reduce<<<256, 256, 0, stream>>>(et, tW1, tb1, tacc, E);
  k_time_combine<<<1, 128, 0, stream>>>(tacc, tW2, tb2, fW1, fb1, cvec, E);

  // x_res = x @ rW + rb  -> d_out
  dim3 gR((N + 63) / 64, 2);
  gemm_f32<<<gR, 256, 0, stream>>>(x, rW, xres, rb, N, 128, 64, 0);

  dim3 gL((N + 63) / 64, 8);
  // layer 1
  gemm_f32<<<gL, 256, 0, stream>>>(x, W1, bufA, nullptr, N, 512, 64, 0);
  k_alar<<<N, 256, 0, stream>>>(bufA, as1, ad1, al, ar);
  k_gat_agg<<<N, 256, 0, stream>>>(bufA, al, ar, offD, lstD, b1, bufB, 0);
  // layer 2
  gemm_f32<<<gL, 256, 0, stream>>>(bufB, W2, bufA, nullptr, N, 512, 512, 0);
  k_alar<<<N, 256, 0, stream>>>(bufA, as2, ad2, al, ar);
  k_gat_agg<<<N, 256, 0, stream>>>(bufA, al, ar, offD, lstD, b2, bufB, 0);
  // layer 3 (head-mean epilogue)
  gemm_f32<<<gL, 256, 0, stream>>>(bufB, W3, bufA, nullptr, N, 512, 512, 0);
  k_alar<<<N, 256, 0, stream>>>(bufA, as3, ad3, al, ar);
  k_gat_agg<<<N, 256, 0, stream>>>(bufA, al, ar, offD, lstD, b3, bufB, 1);

  // agg = segment_sum(h3[dst], src)
  k_aggsrc<<<N, 128, 0, stream>>>(h3, offS, lstS, aggv);

  // z1 = relu(aggv @ fW1[:128] + cvec); z2 = z1 @ fW2 + fb2
  dim3 gF((N + 63) / 64, 2);
  gemm_f32<<<gF, 256, 0, stream>>>(aggv, fW1, z1, cvec, N, 128, 128, 1);
  gemm_f32<<<gF, 256, 0, stream>>>(z1, fW2, z2, fb2, N, 128, 128, 0);

  // layernorm + residual -> d_out
  k_ln_res<<<N, 128, 0, stream>>>(z2, lng, lnb, xres);
}

// Round 2
// 795.008 us; speedup vs baseline: 1.3582x; 1.3582x over previous
//
#include <hip/hip_runtime.h>
#include <hip/hip_bf16.h>
#include <math.h>

typedef short bf16x8 __attribute__((ext_vector_type(8)));
typedef float f32x4 __attribute__((ext_vector_type(4)));

__device__ __forceinline__ float lrelu(float v) { return v > 0.f ? v : 0.2f * v; }

__device__ __forceinline__ void gload16(const void* g, void* l) {
  __builtin_amdgcn_global_load_lds(
      (const __attribute__((address_space(1))) void*)g,
      (__attribute__((address_space(3))) void*)l, 16, 0, 0);
}

// ---------------- init: zero counters ----------------
__global__ void k_init(int* cntD, int* curD, int* cntS, int* curS, float* tacc, int n) {
  int i = blockIdx.x * blockDim.x + threadIdx.x;
  if (i < n) { cntD[i] = 0; curD[i] = 0; cntS[i] = 0; curS[i] = 0; }
  if (i < 64) tacc[i] = 0.f;
}

// ---------------- degree count ----------------
__global__ void k_count(const int* __restrict__ src, const int* __restrict__ dst, int E,
                        int* cntD, int* cntS) {
  int e = blockIdx.x * blockDim.x + threadIdx.x;
  if (e < E) {
    atomicAdd(&cntD[dst[e]], 1);
    atomicAdd(&cntS[src[e]], 1);
  }
}

// ---------------- exclusive scan over n counts (1 block) ----------------
__global__ __launch_bounds__(1024) void k_scan(const int* __restrict__ cnt, int* __restrict__ off, int n) {
  __shared__ int buf[1024];
  __shared__ int carry;
  int t = threadIdx.x;
  if (t == 0) carry = 0;
  __syncthreads();
  for (int base = 0; base < n; base += 1024) {
    int v = (base + t < n) ? cnt[base + t] : 0;
    buf[t] = v;
    __syncthreads();
    for (int o = 1; o < 1024; o <<= 1) {
      int xval = 0;
      if (t >= o) xval = buf[t - o];
      __syncthreads();
      if (t >= o) buf[t] += xval;
      __syncthreads();
    }
    if (base + t < n) off[base + t] = carry + buf[t] - v;
    __syncthreads();
    if (t == 1023) carry += buf[1023];
    __syncthreads();
  }
  if (t == 0) off[n] = carry;
}

// ---------------- fill CSR lists ----------------
__global__ void k_fill(const int* __restrict__ src, const int* __restrict__ dst, int E,
                       const int* __restrict__ offD, int* curD, int* lstD,
                       const int* __restrict__ offS, int* curS, int* lstS) {
  int e = blockIdx.x * blockDim.x + threadIdx.x;
  if (e < E) {
    int d = dst[e], s = src[e];
    int p = atomicAdd(&curD[d], 1);
    lstD[offD[d] + p] = s;
    int q = atomicAdd(&curS[s], 1);
    lstS[offS[s] + q] = d;
  }
}

// ---------------- time embedding: sum_e relu(t*w+b) per k ----------------
__global__ __launch_bounds__(256) void k_time_reduce(const float* __restrict__ et,
    const float* __restrict__ tW1, const float* __restrict__ tb1,
    float* __restrict__ tacc, int E) {
  int t = threadIdx.x;
  int k = t & 63;
  int g = t >> 6;
  float wk = tW1[k], bk = tb1[k];
  float acc = 0.f;
  for (int e = blockIdx.x * 4 + g; e < E; e += gridDim.x * 4) {
    float v = et[e] * wk + bk;
    acc += v > 0.f ? v : 0.f;
  }
  __shared__ float buf[256];
  buf[t] = acc;
  __syncthreads();
  if (t < 64) {
    float s = buf[t] + buf[t + 64] + buf[t + 128] + buf[t + 192];
    atomicAdd(&tacc[t], s);
  }
}

// ---------------- cvec = (mean @ tW2 + tb2) @ fW1[128:] + fb1 ----------------
__global__ __launch_bounds__(128) void k_time_combine(const float* __restrict__ tacc,
    const float* __restrict__ tW2, const float* __restrict__ tb2,
    const float* __restrict__ fW1, const float* __restrict__ fb1,
    float* __restrict__ cvec, int E) {
  __shared__ float tm[128];
  int t = threadIdx.x;
  float inv = 1.f / (float)E;
  float acc = tb2[t];
  for (int k = 0; k < 64; ++k) acc += (tacc[k] * inv) * tW2[k * 128 + t];
  tm[t] = acc;
  __syncthreads();
  float c = fb1[t];
  for (int k = 0; k < 128; ++k) c += tm[k] * fW1[(128 + k) * 128 + t];
  cvec[t] = c;
}

// ---------------- weight convert+transpose: W[K][Nw] f32 -> Wt[Nw][K] bf16 ----------------
__global__ void k_convWt(const float* __restrict__ W, __hip_bfloat16* __restrict__ Wt,
                         int K, int Nw) {
  int i = blockIdx.x * blockDim.x + threadIdx.x;
  if (i < K * Nw) {
    int k = i / Nw, n = i - k * Nw;
    Wt[(size_t)n * K + k] = __float2bfloat16(W[i]);
  }
}

// ---------------- x f32 [N][64] -> bf16 [Mp][64] zero-padded ----------------
__global__ void k_convX(const float* __restrict__ x, __hip_bfloat16* __restrict__ xb,
                        int N, int Mp) {
  int i = blockIdx.x * blockDim.x + threadIdx.x;
  if (i < Mp * 64) {
    int row = i >> 6;
    xb[i] = __float2bfloat16(row < N ? x[i] : 0.f);
  }
}

// ---------------- zero pad rows [N,Mp) of habf(512), aggbf(128), z1bf(128) ----------------
__global__ void k_padzero(__hip_bfloat16* habf, __hip_bfloat16* aggbf, __hip_bfloat16* z1bf,
                          int N, int Mp) {
  int row = N + blockIdx.x;
  int t = threadIdx.x;
  __hip_bfloat16 z = __float2bfloat16(0.f);
  habf[(size_t)row * 512 + t] = z;
  habf[(size_t)row * 512 + t + 256] = z;
  if (t < 128) {
    aggbf[(size_t)row * 128 + t] = z;
    z1bf[(size_t)row * 128 + t] = z;
  }
}

// ---------------- bf16 MFMA GEMM: C[Mp,Nw] = A[Mp,K] @ Bt[Nw,K]^T ----------------
// 128x128 tile, 4 waves each 64x64, 16x16x32 MFMA, global_load_lds staging.
__global__ __launch_bounds__(256) void gemm_bf16(
    const __hip_bfloat16* __restrict__ A, const __hip_bfloat16* __restrict__ Bt,
    void* __restrict__ Cout, const float* __restrict__ bias,
    int M, int Nw, int K, int relu, int outBf)
{
  __shared__ short As[128 * 32];
  __shared__ short Bs[128 * 32];
  int tid = threadIdx.x;
  int bm = blockIdx.x * 128;
  int bn = blockIdx.y * 128;
  int w = tid >> 6, l = tid & 63;
  int wr = (w >> 1) * 64, wc = (w & 1) * 64;
  f32x4 acc[4][4] = {};
  const short* Ag = (const short*)A;
  const short* Bg = (const short*)Bt;

  for (int k0 = 0; k0 < K; k0 += 32) {
#pragma unroll
    for (int i = 0; i < 2; ++i) {
      int slot = i * 256 + tid;
      int row = slot >> 2;
      int col = (slot & 3) * 8;
      gload16(Ag + (size_t)(bm + row) * K + k0 + col, &As[slot * 8]);
      gload16(Bg + (size_t)(bn + row) * K + k0 + col, &Bs[slot * 8]);
    }
    __syncthreads();
    bf16x8 af[4], bfr[4];
#pragma unroll
    for (int m = 0; m < 4; ++m)
      af[m] = *(const bf16x8*)&As[(wr + m * 16 + (l & 15)) * 32 + (l >> 4) * 8];
#pragma unroll
    for (int n = 0; n < 4; ++n)
      bfr[n] = *(const bf16x8*)&Bs[(wc + n * 16 + (l & 15)) * 32 + (l >> 4) * 8];
#pragma unroll
    for (int m = 0; m < 4; ++m)
#pragma unroll
      for (int n = 0; n < 4; ++n)
        acc[m][n] = __builtin_amdgcn_mfma_f32_16x16x32_bf16(af[m], bfr[n], acc[m][n], 0, 0, 0);
    __syncthreads();
  }

  int cr = (l >> 4) * 4;
  int cc = l & 15;
#pragma unroll
  for (int n = 0; n < 4; ++n) {
    int col = bn + wc + n * 16 + cc;
    float bb = bias ? bias[col] : 0.f;
#pragma unroll
    for (int m = 0; m < 4; ++m) {
      int gmb = bm + wr + m * 16 + cr;
#pragma unroll
      for (int r = 0; r < 4; ++r) {
        int gm = gmb + r;
        if (gm < M) {
          float v = acc[m][n][r] + bb;
          if (relu) v = fmaxf(v, 0.f);
          if (outBf) ((__hip_bfloat16*)Cout)[(size_t)gm * Nw + col] = __float2bfloat16(v);
          else ((float*)Cout)[(size_t)gm * Nw + col] = v;
        }
      }
    }
  }
}

// ---------------- per-node attention dots (xl bf16) ----------------
__global__ __launch_bounds__(256) void k_alar(const __hip_bfloat16* __restrict__ xl,
    const float* __restrict__ asrc, const float* __restrict__ adst,
    float* __restrict__ al, float* __restrict__ ar) {
  int n = blockIdx.x;
  int t = threadIdx.x;
  int h = t >> 6, l = t & 63;
  const __hip_bfloat16* xr = xl + (size_t)n * 512 + h * 128;
  float x0 = __bfloat162float(xr[l]);
  float x1 = __bfloat162float(xr[l + 64]);
  const float* as_ = asrc + h * 128;
  const float* ad_ = adst + h * 128;
  float a1 = x0 * as_[l] + x1 * as_[l + 64];
  float a2 = x0 * ad_[l] + x1 * ad_[l + 64];
#pragma unroll
  for (int o = 32; o; o >>= 1) { a1 += __shfl_down(a1, o); a2 += __shfl_down(a2, o); }
  if (l == 0) { al[n * 4 + h] = a1; ar[n * 4 + h] = a2; }
}

// ---------------- GAT aggregation per dst node (xl bf16) ----------------
// mode 0: outb = bf16(relu(agg512 + bias512))   (Mp x 512 bf16)
// mode 1: outf = relu(mean_heads(agg512) + bias128)  (N x 128 f32)
__global__ __launch_bounds__(256) void k_gat_agg(
    const __hip_bfloat16* __restrict__ xl, const float* __restrict__ al, const float* __restrict__ ar,
    const int* __restrict__ off, const int* __restrict__ lst,
    const float* __restrict__ bias, __hip_bfloat16* __restrict__ outb,
    float* __restrict__ outf, int mode)
{
  __shared__ float sm[256][4];
  __shared__ float ss[256][4];
  __shared__ float mxs[4], invs[4];
  __shared__ float tmp[512];
  int d = blockIdx.x;
  int t = threadIdx.x;
  int base = off[d];
  int deg = off[d + 1] - base;
  float ar0 = ar[4 * d + 0], ar1 = ar[4 * d + 1], ar2 = ar[4 * d + 2], ar3 = ar[4 * d + 3];

  float m0 = -1e30f, m1 = -1e30f, m2 = -1e30f, m3 = -1e30f;
  float s0 = 0.f, s1 = 0.f, s2 = 0.f, s3 = 0.f;
  if (t == 0) {
    float4 av = *reinterpret_cast<const float4*>(&al[4 * d]);
    m0 = lrelu(av.x + ar0); s0 = 1.f;
    m1 = lrelu(av.y + ar1); s1 = 1.f;
    m2 = lrelu(av.z + ar2); s2 = 1.f;
    m3 = lrelu(av.w + ar3); s3 = 1.f;
  }
  for (int j = t; j < deg; j += 256) {
    int sid = lst[base + j];
    float4 av = *reinterpret_cast<const float4*>(&al[4 * sid]);
    float lg;
    lg = lrelu(av.x + ar0);
    if (lg > m0) { s0 = s0 * __expf(m0 - lg) + 1.f; m0 = lg; } else s0 += __expf(lg - m0);
    lg = lrelu(av.y + ar1);
    if (lg > m1) { s1 = s1 * __expf(m1 - lg) + 1.f; m1 = lg; } else s1 += __expf(lg - m1);
    lg = lrelu(av.z + ar2);
    if (lg > m2) { s2 = s2 * __expf(m2 - lg) + 1.f; m2 = lg; } else s2 += __expf(lg - m2);
    lg = lrelu(av.w + ar3);
    if (lg > m3) { s3 = s3 * __expf(m3 - lg) + 1.f; m3 = lg; } else s3 += __expf(lg - m3);
  }
  sm[t][0] = m0; ss[t][0] = s0;
  sm[t][1] = m1; ss[t][1] = s1;
  sm[t][2] = m2; ss[t][2] = s2;
  sm[t][3] = m3; ss[t][3] = s3;
  __syncthreads();
  for (int str = 128; str; str >>= 1) {
    if (t < str) {
#pragma unroll
      for (int h = 0; h < 4; ++h) {
        float ma = sm[t][h], sa = ss[t][h];
        float mb = sm[t + str][h], sb = ss[t + str][h];
        float M = fmaxf(ma, mb);
        ss[t][h] = sa * __expf(ma - M) + sb * __expf(mb - M);
        sm[t][h] = M;
      }
    }
    __syncthreads();
  }
  if (t < 4) { mxs[t] = sm[0][t]; invs[t] = 1.f / ss[0][t]; }
  __syncthreads();

  int c0 = t, c1 = t + 256;
  int h0 = t >> 7, h1 = h0 + 2;
  float mh0 = mxs[h0], mh1 = mxs[h1];
  float i0 = invs[h0], i1 = invs[h1];
  float arh0 = ar[4 * d + h0], arh1 = ar[4 * d + h1];
  float acc0 = 0.f, acc1 = 0.f;
  for (int j = 0; j < deg; ++j) {
    int sid = lst[base + j];
    float a0 = __expf(lrelu(al[4 * sid + h0] + arh0) - mh0) * i0;
    float a1 = __expf(lrelu(al[4 * sid + h1] + arh1) - mh1) * i1;
    const __hip_bfloat16* xr = xl + (size_t)sid * 512;
    acc0 += a0 * __bfloat162float(xr[c0]);
    acc1 += a1 * __bfloat162float(xr[c1]);
  }
  {
    float a0 = __expf(lrelu(al[4 * d + h0] + arh0) - mh0) * i0;
    float a1 = __expf(lrelu(al[4 * d + h1] + arh1) - mh1) * i1;
    const __hip_bfloat16* xr = xl + (size_t)d * 512;
    acc0 += a0 * __bfloat162float(xr[c0]);
    acc1 += a1 * __bfloat162float(xr[c1]);
  }
  if (mode == 0) {
    outb[(size_t)d * 512 + c0] = __float2bfloat16(fmaxf(acc0 + bias[c0], 0.f));
    outb[(size_t)d * 512 + c1] = __float2bfloat16(fmaxf(acc1 + bias[c1], 0.f));
  } else {
    tmp[c0] = acc0; tmp[c1] = acc1;
    __syncthreads();
    if (t < 128) {
      float v = (tmp[t] + tmp[t + 128] + tmp[t + 256] + tmp[t + 384]) * 0.25f + bias[t];
      outf[(size_t)d * 128 + t] = fmaxf(v, 0.f);
    }
  }
}

// ---------------- final src-side segment sum -> bf16 ----------------
__global__ __launch_bounds__(128) void k_aggsrc(const float* __restrict__ h3,
    const int* __restrict__ off, const int* __restrict__ lst,
    __hip_bfloat16* __restrict__ out) {
  int n = blockIdx.x, t = threadIdx.x;
  float acc = h3[(size_t)n * 128 + t];
  int b = off[n], e = off[n + 1];
  for (int j = b; j < e; ++j) acc += h3[(size_t)lst[j] * 128 + t];
  out[(size_t)n * 128 + t] = __float2bfloat16(acc);
}

// ---------------- layernorm + residual (out holds x_res, overwritten) ----------------
__global__ __launch_bounds__(128) void k_ln_res(const float* __restrict__ z,
    const float* __restrict__ g, const float* __restrict__ bt, float* __restrict__ out) {
  int n = blockIdx.x, t = threadIdx.x;
  float v = z[(size_t)n * 128 + t];
  __shared__ float red[2];
  float s = v;
#pragma unroll
  for (int o = 32; o; o >>= 1) s += __shfl_down(s, o);
  if ((t & 63) == 0) red[t >> 6] = s;
  __syncthreads();
  float mu = (red[0] + red[1]) * (1.f / 128.f);
  float dv = v - mu;
  float q = dv * dv;
  __syncthreads();
#pragma unroll
  for (int o = 32; o; o >>= 1) q += __shfl_down(q, o);
  if ((t & 63) == 0) red[t >> 6] = q;
  __syncthreads();
  float var = (red[0] + red[1]) * (1.f / 128.f);
  float y = dv * rsqrtf(var + 1e-5f) * g[t] + bt[t];
  out[(size_t)n * 128 + t] = y + out[(size_t)n * 128 + t];
}

extern "C" void kernel_launch(void* const* d_in, const int* in_sizes, int n_in,
                              void* d_out, int out_size, void* d_ws, size_t ws_size,
                              hipStream_t stream) {
  (void)n_in; (void)out_size; (void)ws_size;
  const float* x   = (const float*)d_in[0];
  const float* et  = (const float*)d_in[1];
  const float* W1  = (const float*)d_in[2];
  const float* as1 = (const float*)d_in[3];
  const float* ad1 = (const float*)d_in[4];
  const float* b1  = (const float*)d_in[5];
  const float* W2  = (const float*)d_in[6];
  const float* as2 = (const float*)d_in[7];
  const float* ad2 = (const float*)d_in[8];
  const float* b2  = (const float*)d_in[9];
  const float* W3  = (const float*)d_in[10];
  const float* as3 = (const float*)d_in[11];
  const float* ad3 = (const float*)d_in[12];
  const float* b3  = (const float*)d_in[13];
  const float* tW1 = (const float*)d_in[14];
  const float* tb1 = (const float*)d_in[15];
  const float* tW2 = (const float*)d_in[16];
  const float* tb2 = (const float*)d_in[17];
  const float* fW1 = (const float*)d_in[18];
  const float* fb1 = (const float*)d_in[19];
  const float* fW2 = (const float*)d_in[20];
  const float* fb2 = (const float*)d_in[21];
  const float* lng = (const float*)d_in[22];
  const float* lnb = (const float*)d_in[23];
  const float* rW  = (const float*)d_in[24];
  const float* rb  = (const float*)d_in[25];
  const int*   ei  = (const int*)d_in[26];
  const int N = in_sizes[0] / 64;     // 20000
  const int E = in_sizes[26] / 2;     // 320000
  const int Mp = ((N + 127) / 128) * 128;  // 20096
  const int* src = ei;
  const int* dst = ei + E;

  char* cur = (char*)d_ws;
  auto carve = [&](size_t bytes) { char* p = cur; cur += (bytes + 255) & ~(size_t)255; return p; };
  __hip_bfloat16* xbf  = (__hip_bfloat16*)carve((size_t)Mp * 64 * 2);
  __hip_bfloat16* habf = (__hip_bfloat16*)carve((size_t)Mp * 512 * 2);
  __hip_bfloat16* xlbf = (__hip_bfloat16*)carve((size_t)Mp * 512 * 2);
  __hip_bfloat16* wt1  = (__hip_bfloat16*)carve((size_t)512 * 64 * 2);
  __hip_bfloat16* wt2  = (__hip_bfloat16*)carve((size_t)512 * 512 * 2);
  __hip_bfloat16* wt3  = (__hip_bfloat16*)carve((size_t)512 * 512 * 2);
  __hip_bfloat16* wtR  = (__hip_bfloat16*)carve((size_t)128 * 64 * 2);
  __hip_bfloat16* wtF1 = (__hip_bfloat16*)carve((size_t)128 * 128 * 2);
  __hip_bfloat16* wtF2 = (__hip_bfloat16*)carve((size_t)128 * 128 * 2);
  __hip_bfloat16* aggbf= (__hip_bfloat16*)carve((size_t)Mp * 128 * 2);
  __hip_bfloat16* z1bf = (__hip_bfloat16*)carve((size_t)Mp * 128 * 2);
  float* h3   = (float*)carve((size_t)N * 128 * 4);
  float* z2   = (float*)carve((size_t)N * 128 * 4);
  float* al   = (float*)carve((size_t)N * 4 * 4);
  float* ar   = (float*)carve((size_t)N * 4 * 4);
  float* tacc = (float*)carve(64 * 4);
  float* cvec = (float*)carve(128 * 4);
  int* cntD = (int*)carve((size_t)N * 4);
  int* offD = (int*)carve((size_t)(N + 1) * 4);
  int* curD = (int*)carve((size_t)N * 4);
  int* lstD = (int*)carve((size_t)E * 4);
  int* cntS = (int*)carve((size_t)N * 4);
  int* offS = (int*)carve((size_t)(N + 1) * 4);
  int* curS = (int*)carve((size_t)N * 4);
  int* lstS = (int*)carve((size_t)E * 4);
  float* xres = (float*)d_out;

  // CSR build
  k_init<<<(N + 255) / 256, 256, 0, stream>>>(cntD, curD, cntS, curS, tacc, N);
  k_count<<<(E + 255) / 256, 256, 0, stream>>>(src, dst, E, cntD, cntS);
  k_scan<<<1, 1024, 0, stream>>>(cntD, offD, N);
  k_scan<<<1, 1024, 0, stream>>>(cntS, offS, N);
  k_fill<<<(E + 255) / 256, 256, 0, stream>>>(src, dst, E, offD, curD, lstD, offS, curS, lstS);

  // time path -> cvec
  k_time_reduce<<<256, 256, 0, stream>>>(et, tW1, tb1, tacc, E);
  k_time_combine<<<1, 128, 0, stream>>>(tacc, tW2, tb2, fW1, fb1, cvec, E);

  // conversions
  k_convX<<<(Mp * 64 + 255) / 256, 256, 0, stream>>>(x, xbf, N, Mp);
  k_padzero<<<Mp - N, 256, 0, stream>>>(habf, aggbf, z1bf, N, Mp);
  k_convWt<<<(64 * 512 + 255) / 256, 256, 0, stream>>>(W1, wt1, 64, 512);
  k_convWt<<<(512 * 512 + 255) / 256, 256, 0, stream>>>(W2, wt2, 512, 512);
  k_convWt<<<(512 * 512 + 255) / 256, 256, 0, stream>>>(W3, wt3, 512, 512);
  k_convWt<<<(64 * 128 + 255) / 256, 256, 0, stream>>>(rW, wtR, 64, 128);
  k_convWt<<<(128 * 128 + 255) / 256, 256, 0, stream>>>(fW1, wtF1, 128, 128);
  k_convWt<<<(128 * 128 + 255) / 256, 256, 0, stream>>>(fW2, wtF2, 128, 128);

  const int TB = Mp / 128;  // 157
  // x_res = x @ rW + rb -> d_out (f32)
  {
    dim3 g(TB, 1);
    gemm_bf16<<<g, 256, 0, stream>>>(xbf, wtR, xres, rb, N, 128, 64, 0, 0);
  }
  // layer 1
  {
    dim3 g(TB, 4);
    gemm_bf16<<<g, 256, 0, stream>>>(xbf, wt1, xlbf, nullptr, Mp, 512, 64, 0, 1);
  }
  k_alar<<<N, 256, 0, stream>>>(xlbf, as1, ad1, al, ar);
  k_gat_agg<<<N, 256, 0, stream>>>(xlbf, al, ar, offD, lstD, b1, habf, nullptr, 0);
  // layer 2
  {
    dim3 g(TB, 4);
    gemm_bf16<<<g, 256, 0, stream>>>(habf, wt2, xlbf, nullptr, Mp, 512, 512, 0, 1);
  }
  k_alar<<<N, 256, 0, stream>>>(xlbf, as2, ad2, al, ar);
  k_gat_agg<<<N, 256, 0, stream>>>(xlbf, al, ar, offD, lstD, b2, habf, nullptr, 0);
  // layer 3 (head-mean epilogue, f32 out)
  {
    dim3 g(TB, 4);
    gemm_bf16<<<g, 256, 0, stream>>>(habf, wt3, xlbf, nullptr, Mp, 512, 512, 0, 1);
  }
  k_alar<<<N, 256, 0, stream>>>(xlbf, as3, ad3, al, ar);
  k_gat_agg<<<N, 256, 0, stream>>>(xlbf, al, ar, offD, lstD, b3, nullptr, h3, 1);

  // agg = segment_sum(h3[dst], src) -> bf16
  k_aggsrc<<<N, 128, 0, stream>>>(h3, offS, lstS, aggbf);

  // z1 = relu(agg @ fW1[:128] + cvec) (bf16); z2 = z1 @ fW2 + fb2 (f32)
  {
    dim3 g(TB, 1);
    gemm_bf16<<<g, 256, 0, stream>>>(aggbf, wtF1, z1bf, cvec, Mp, 128, 128, 1, 1);
    gemm_bf16<<<g, 256, 0, stream>>>(z1bf, wtF2, z2, fb2, N, 128, 128, 0, 0);
  }

  // layernorm + residual -> d_out
  k_ln_res<<<N, 128, 0, stream>>>(z2, lng, lnb, xres);
}

// Round 3
// 597.024 us; speedup vs baseline: 1.8086x; 1.3316x over previous
//
#include <hip/hip_runtime.h>
#include <hip/hip_bf16.h>
#include <math.h>

typedef short bf16x8 __attribute__((ext_vector_type(8)));
typedef float f32x4 __attribute__((ext_vector_type(4)));

__device__ __forceinline__ float lrelu(float v) { return v > 0.f ? v : 0.2f * v; }

__device__ __forceinline__ void gload16(const void* g, void* l) {
  __builtin_amdgcn_global_load_lds(
      (const __attribute__((address_space(1))) void*)g,
      (__attribute__((address_space(3))) void*)l, 16, 0, 0);
}

// ---------------- init: zero counters ----------------
__global__ void k_init(int* cntD, int* curD, int* cntS, int* curS, float* tacc, int n) {
  int i = blockIdx.x * blockDim.x + threadIdx.x;
  if (i < n) { cntD[i] = 0; curD[i] = 0; cntS[i] = 0; curS[i] = 0; }
  if (i < 64) tacc[i] = 0.f;
}

// ---------------- degree count ----------------
__global__ void k_count(const int* __restrict__ src, const int* __restrict__ dst, int E,
                        int* cntD, int* cntS) {
  int e = blockIdx.x * blockDim.x + threadIdx.x;
  if (e < E) {
    atomicAdd(&cntD[dst[e]], 1);
    atomicAdd(&cntS[src[e]], 1);
  }
}

// ---------------- exclusive scan, single block, ~20 barriers ----------------
__global__ __launch_bounds__(1024) void k_scan(const int* __restrict__ cnt, int* __restrict__ off, int n) {
  __shared__ int sums[1024];
  int t = threadIdx.x;
  int PT = (n + 1023) >> 10;
  int start = t * PT;
  int local = 0;
  for (int i = 0; i < PT; ++i) {
    int idx = start + i;
    if (idx < n) local += cnt[idx];
  }
  sums[t] = local;
  __syncthreads();
  for (int o = 1; o < 1024; o <<= 1) {
    int v = (t >= o) ? sums[t - o] : 0;
    __syncthreads();
    sums[t] += v;
    __syncthreads();
  }
  int run = sums[t] - local;  // exclusive prefix of this thread's chunk
  for (int i = 0; i < PT; ++i) {
    int idx = start + i;
    if (idx < n) { off[idx] = run; run += cnt[idx]; }
  }
  if (t == 1023) off[n] = run;
}

// ---------------- fill CSR lists ----------------
__global__ void k_fill(const int* __restrict__ src, const int* __restrict__ dst, int E,
                       const int* __restrict__ offD, int* curD, int* lstD,
                       const int* __restrict__ offS, int* curS, int* lstS) {
  int e = blockIdx.x * blockDim.x + threadIdx.x;
  if (e < E) {
    int d = dst[e], s = src[e];
    int p = atomicAdd(&curD[d], 1);
    lstD[offD[d] + p] = s;
    int q = atomicAdd(&curS[s], 1);
    lstS[offS[s] + q] = d;
  }
}

// ---------------- time embedding: sum_e relu(t*w+b) per k (shfl broadcast) ----------------
__global__ __launch_bounds__(256) void k_time_reduce(const float* __restrict__ et,
    const float* __restrict__ tW1, const float* __restrict__ tb1,
    float* __restrict__ tacc, int E) {
  int t = threadIdx.x;
  int l = t & 63;
  float wk = tW1[l], bk = tb1[l];
  float acc = 0.f;
  int gw = (blockIdx.x * 256 + t) >> 6;   // global wave id
  int nw = gridDim.x * 4;
  for (int base = gw * 64; base < E; base += nw * 64) {
    int idx = base + l;
    float v = (idx < E) ? et[idx] : 0.f;
    int cnt = E - base; if (cnt > 64) cnt = 64;
    for (int j = 0; j < cnt; ++j) {
      float tv = __shfl(v, j);
      float u = tv * wk + bk;
      acc += fmaxf(u, 0.f);
    }
  }
  __shared__ float buf[256];
  buf[t] = acc;
  __syncthreads();
  if (t < 64) {
    float s = buf[t] + buf[t + 64] + buf[t + 128] + buf[t + 192];
    atomicAdd(&tacc[t], s);
  }
}

// ---------------- cvec = (mean @ tW2 + tb2) @ fW1[128:] + fb1 ----------------
__global__ __launch_bounds__(128) void k_time_combine(const float* __restrict__ tacc,
    const float* __restrict__ tW2, const float* __restrict__ tb2,
    const float* __restrict__ fW1, const float* __restrict__ fb1,
    float* __restrict__ cvec, int E) {
  __shared__ float tm[128];
  int t = threadIdx.x;
  float inv = 1.f / (float)E;
  float acc = tb2[t];
  for (int k = 0; k < 64; ++k) acc += (tacc[k] * inv) * tW2[k * 128 + t];
  tm[t] = acc;
  __syncthreads();
  float c = fb1[t];
  for (int k = 0; k < 128; ++k) c += tm[k] * fW1[(128 + k) * 128 + t];
  cvec[t] = c;
}

// ---------------- weight convert+transpose (LDS tiled): W[K][Nw] f32 -> Wt[Nw][K] bf16 ----
// requires K%32==0, Nw%64==0
__global__ __launch_bounds__(256) void k_convWt(const float* __restrict__ W,
    __hip_bfloat16* __restrict__ Wt, int K, int Nw) {
  __shared__ float tile[32][65];
  int bk = blockIdx.x * 32;
  int bn = blockIdx.y * 64;
  int t = threadIdx.x;
  int rn = t & 63, rk = t >> 6;
#pragma unroll
  for (int i = 0; i < 8; ++i) {
    int k = rk + i * 4;
    tile[k][rn] = W[(size_t)(bk + k) * Nw + bn + rn];
  }
  __syncthreads();
  int wk2 = (t & 15) * 2;
  int wn = t >> 4;
  uint* Wo = (uint*)Wt;
#pragma unroll
  for (int i = 0; i < 4; ++i) {
    int n = wn + i * 16;
    __hip_bfloat16 h0 = __float2bfloat16(tile[wk2][n]);
    __hip_bfloat16 h1 = __float2bfloat16(tile[wk2 + 1][n]);
    uint p = (uint)(*(unsigned short*)&h0) | ((uint)(*(unsigned short*)&h1) << 16);
    Wo[((size_t)(bn + n) * K + bk + wk2) >> 1] = p;
  }
}

// ---------------- x f32 [N][64] -> bf16 [Mp][64] zero-padded ----------------
__global__ void k_convX(const float* __restrict__ x, __hip_bfloat16* __restrict__ xb,
                        int N, int Mp) {
  int i = blockIdx.x * blockDim.x + threadIdx.x;
  if (i < Mp * 64) {
    int row = i >> 6;
    xb[i] = __float2bfloat16(row < N ? x[i] : 0.f);
  }
}

// ---------------- zero pad rows [N,Mp) ----------------
__global__ void k_padzero(__hip_bfloat16* habf, __hip_bfloat16* aggbf, __hip_bfloat16* z1bf,
                          int N, int Mp) {
  int row = N + blockIdx.x;
  int t = threadIdx.x;
  __hip_bfloat16 z = __float2bfloat16(0.f);
  habf[(size_t)row * 512 + t] = z;
  habf[(size_t)row * 512 + t + 256] = z;
  if (t < 128) {
    aggbf[(size_t)row * 128 + t] = z;
    z1bf[(size_t)row * 128 + t] = z;
  }
}

// ---------------- bf16 MFMA GEMM: C[Mp,Nw] = A[Mp,K] @ Bt[Nw,K]^T ----------------
__global__ __launch_bounds__(256) void gemm_bf16(
    const __hip_bfloat16* __restrict__ A, const __hip_bfloat16* __restrict__ Bt,
    void* __restrict__ Cout, const float* __restrict__ bias,
    int M, int Nw, int K, int relu, int outBf)
{
  __shared__ short As[128 * 32];
  __shared__ short Bs[128 * 32];
  int tid = threadIdx.x;
  int bm = blockIdx.x * 128;
  int bn = blockIdx.y * 128;
  int w = tid >> 6, l = tid & 63;
  int wr = (w >> 1) * 64, wc = (w & 1) * 64;
  f32x4 acc[4][4] = {};
  const short* Ag = (const short*)A;
  const short* Bg = (const short*)Bt;

  for (int k0 = 0; k0 < K; k0 += 32) {
#pragma unroll
    for (int i = 0; i < 2; ++i) {
      int slot = i * 256 + tid;
      int row = slot >> 2;
      int col = (slot & 3) * 8;
      gload16(Ag + (size_t)(bm + row) * K + k0 + col, &As[slot * 8]);
      gload16(Bg + (size_t)(bn + row) * K + k0 + col, &Bs[slot * 8]);
    }
    __syncthreads();
    bf16x8 af[4], bfr[4];
#pragma unroll
    for (int m = 0; m < 4; ++m)
      af[m] = *(const bf16x8*)&As[(wr + m * 16 + (l & 15)) * 32 + (l >> 4) * 8];
#pragma unroll
    for (int n = 0; n < 4; ++n)
      bfr[n] = *(const bf16x8*)&Bs[(wc + n * 16 + (l & 15)) * 32 + (l >> 4) * 8];
#pragma unroll
    for (int m = 0; m < 4; ++m)
#pragma unroll
      for (int n = 0; n < 4; ++n)
        acc[m][n] = __builtin_amdgcn_mfma_f32_16x16x32_bf16(af[m], bfr[n], acc[m][n], 0, 0, 0);
    __syncthreads();
  }

  int cr = (l >> 4) * 4;
  int cc = l & 15;
#pragma unroll
  for (int n = 0; n < 4; ++n) {
    int col = bn + wc + n * 16 + cc;
    float bb = bias ? bias[col] : 0.f;
#pragma unroll
    for (int m = 0; m < 4; ++m) {
      int gmb = bm + wr + m * 16 + cr;
#pragma unroll
      for (int r = 0; r < 4; ++r) {
        int gm = gmb + r;
        if (gm < M) {
          float v = acc[m][n][r] + bb;
          if (relu) v = fmaxf(v, 0.f);
          if (outBf) ((__hip_bfloat16*)Cout)[(size_t)gm * Nw + col] = __float2bfloat16(v);
          else ((float*)Cout)[(size_t)gm * Nw + col] = v;
        }
      }
    }
  }
}

// ---------------- per-node attention dots (wave per node, bf16x8 loads) ----------------
__global__ __launch_bounds__(256) void k_alar(const __hip_bfloat16* __restrict__ xl,
    const float* __restrict__ asrc, const float* __restrict__ adst,
    float* __restrict__ al, float* __restrict__ ar, int N) {
  int w = threadIdx.x >> 6, l = threadIdx.x & 63;
  int n = blockIdx.x * 4 + w;
  if (n >= N) return;
  bf16x8 xv = *(const bf16x8*)((const short*)xl + (size_t)n * 512 + l * 8);
  float4 a0 = *(const float4*)(asrc + l * 8);
  float4 a1 = *(const float4*)(asrc + l * 8 + 4);
  float4 d0 = *(const float4*)(adst + l * 8);
  float4 d1 = *(const float4*)(adst + l * 8 + 4);
  float xs[8];
#pragma unroll
  for (int j = 0; j < 8; ++j)
    xs[j] = __uint_as_float(((uint)(unsigned short)xv[j]) << 16);
  float s1 = xs[0]*a0.x + xs[1]*a0.y + xs[2]*a0.z + xs[3]*a0.w
           + xs[4]*a1.x + xs[5]*a1.y + xs[6]*a1.z + xs[7]*a1.w;
  float s2 = xs[0]*d0.x + xs[1]*d0.y + xs[2]*d0.z + xs[3]*d0.w
           + xs[4]*d1.x + xs[5]*d1.y + xs[6]*d1.z + xs[7]*d1.w;
#pragma unroll
  for (int o = 1; o < 16; o <<= 1) {
    s1 += __shfl_xor(s1, o);
    s2 += __shfl_xor(s2, o);
  }
  if ((l & 15) == 0) {
    al[n * 4 + (l >> 4)] = s1;
    ar[n * 4 + (l >> 4)] = s2;
  }
}

// ---------------- GAT aggregation per dst node (alpha staged in LDS) ----------------
// self-loop handled as virtual edge index j==deg.
// mode 0: outb = bf16(relu(agg512 + bias512))   (row-major 512)
// mode 1: outf = relu(mean_heads(agg512) + bias128)
__global__ __launch_bounds__(256) void k_gat_agg(
    const __hip_bfloat16* __restrict__ xl, const float* __restrict__ al, const float* __restrict__ ar,
    const int* __restrict__ off, const int* __restrict__ lst,
    const float* __restrict__ bias, __hip_bfloat16* __restrict__ outb,
    float* __restrict__ outf, int mode)
{
  __shared__ int   ssid[256];
  __shared__ float salpha[256][4];
  __shared__ float redm[4][4], reds[4][4];
  __shared__ float mxs[4], invs[4];
  __shared__ float tmp[512];
  int d = blockIdx.x, t = threadIdx.x;
  int l = t & 63, w = t >> 6;
  int base = off[d];
  int deg = off[d + 1] - base;
  float4 arv = *(const float4*)(ar + 4 * d);

  // phase 1: per-thread online softmax stats over edges (incl. virtual self at j==deg)
  float m[4] = {-1e30f, -1e30f, -1e30f, -1e30f};
  float s[4] = {0.f, 0.f, 0.f, 0.f};
  for (int j = t; j <= deg; j += 256) {
    int sid = (j == deg) ? d : lst[base + j];
    float4 av = *(const float4*)(al + 4 * sid);
    float lg;
    lg = lrelu(av.x + arv.x);
    if (lg > m[0]) { s[0] = s[0] * __expf(m[0] - lg) + 1.f; m[0] = lg; } else s[0] += __expf(lg - m[0]);
    lg = lrelu(av.y + arv.y);
    if (lg > m[1]) { s[1] = s[1] * __expf(m[1] - lg) + 1.f; m[1] = lg; } else s[1] += __expf(lg - m[1]);
    lg = lrelu(av.z + arv.z);
    if (lg > m[2]) { s[2] = s[2] * __expf(m[2] - lg) + 1.f; m[2] = lg; } else s[2] += __expf(lg - m[2]);
    lg = lrelu(av.w + arv.w);
    if (lg > m[3]) { s[3] = s[3] * __expf(m[3] - lg) + 1.f; m[3] = lg; } else s[3] += __expf(lg - m[3]);
  }
#pragma unroll
  for (int o = 1; o < 64; o <<= 1) {
#pragma unroll
    for (int h = 0; h < 4; ++h) {
      float mo = __shfl_xor(m[h], o);
      float so = __shfl_xor(s[h], o);
      float M = fmaxf(m[h], mo);
      s[h] = s[h] * __expf(m[h] - M) + so * __expf(mo - M);
      m[h] = M;
    }
  }
  if (l == 0) {
#pragma unroll
    for (int h = 0; h < 4; ++h) { redm[w][h] = m[h]; reds[w][h] = s[h]; }
  }
  __syncthreads();
  if (t < 4) {
    float M = fmaxf(fmaxf(redm[0][t], redm[1][t]), fmaxf(redm[2][t], redm[3][t]));
    float S = reds[0][t] * __expf(redm[0][t] - M) + reds[1][t] * __expf(redm[1][t] - M)
            + reds[2][t] * __expf(redm[2][t] - M) + reds[3][t] * __expf(redm[3][t] - M);
    mxs[t] = M; invs[t] = 1.f / S;
  }
  __syncthreads();

  // phase 2: chunked alpha staging + gather
  int hh = t >> 6;
  float acc0 = 0.f, acc1 = 0.f;
  const uint* xw = (const uint*)xl;
  for (int cb = 0; cb <= deg; cb += 256) {
    int j = cb + t;
    if (j <= deg) {
      int sid = (j == deg) ? d : lst[base + j];
      ssid[t] = sid;
      float4 av = *(const float4*)(al + 4 * sid);
      salpha[t][0] = __expf(lrelu(av.x + arv.x) - mxs[0]) * invs[0];
      salpha[t][1] = __expf(lrelu(av.y + arv.y) - mxs[1]) * invs[1];
      salpha[t][2] = __expf(lrelu(av.z + arv.z) - mxs[2]) * invs[2];
      salpha[t][3] = __expf(lrelu(av.w + arv.w) - mxs[3]) * invs[3];
    }
    __syncthreads();
    int cnt = deg + 1 - cb; if (cnt > 256) cnt = 256;
#pragma unroll 4
    for (int jj = 0; jj < cnt; ++jj) {
      int sid = ssid[jj];
      float a = salpha[jj][hh];
      uint pv = xw[(size_t)sid * 256 + t];
      acc0 += a * __uint_as_float(pv << 16);
      acc1 += a * __uint_as_float(pv & 0xffff0000u);
    }
    __syncthreads();
  }

  int c0 = 2 * t, c1 = 2 * t + 1;
  if (mode == 0) {
    float v0 = fmaxf(acc0 + bias[c0], 0.f);
    float v1 = fmaxf(acc1 + bias[c1], 0.f);
    __hip_bfloat16 h0 = __float2bfloat16(v0);
    __hip_bfloat16 h1 = __float2bfloat16(v1);
    uint p = (uint)(*(unsigned short*)&h0) | ((uint)(*(unsigned short*)&h1) << 16);
    ((uint*)outb)[(size_t)d * 256 + t] = p;
  } else {
    tmp[c0] = acc0; tmp[c1] = acc1;
    __syncthreads();
    if (t < 128) {
      float v = (tmp[t] + tmp[t + 128] + tmp[t + 256] + tmp[t + 384]) * 0.25f + bias[t];
      outf[(size_t)d * 128 + t] = fmaxf(v, 0.f);
    }
  }
}

// ---------------- final src-side segment sum -> bf16 ----------------
__global__ __launch_bounds__(128) void k_aggsrc(const float* __restrict__ h3,
    const int* __restrict__ off, const int* __restrict__ lst,
    __hip_bfloat16* __restrict__ out) {
  int n = blockIdx.x, t = threadIdx.x;
  float acc = h3[(size_t)n * 128 + t];
  int b = off[n], e = off[n + 1];
  for (int j = b; j < e; ++j) acc += h3[(size_t)lst[j] * 128 + t];
  out[(size_t)n * 128 + t] = __float2bfloat16(acc);
}

// ---------------- layernorm + residual (out holds x_res, overwritten) ----------------
__global__ __launch_bounds__(128) void k_ln_res(const float* __restrict__ z,
    const float* __restrict__ g, const float* __restrict__ bt, float* __restrict__ out) {
  int n = blockIdx.x, t = threadIdx.x;
  float v = z[(size_t)n * 128 + t];
  __shared__ float red[2];
  float s = v;
#pragma unroll
  for (int o = 32; o; o >>= 1) s += __shfl_down(s, o);
  if ((t & 63) == 0) red[t >> 6] = s;
  __syncthreads();
  float mu = (red[0] + red[1]) * (1.f / 128.f);
  float dv = v - mu;
  float q = dv * dv;
  __syncthreads();
#pragma unroll
  for (int o = 32; o; o >>= 1) q += __shfl_down(q, o);
  if ((t & 63) == 0) red[t >> 6] = q;
  __syncthreads();
  float var = (red[0] + red[1]) * (1.f / 128.f);
  float y = dv * rsqrtf(var + 1e-5f) * g[t] + bt[t];
  out[(size_t)n * 128 + t] = y + out[(size_t)n * 128 + t];
}

extern "C" void kernel_launch(void* const* d_in, const int* in_sizes, int n_in,
                              void* d_out, int out_size, void* d_ws, size_t ws_size,
                              hipStream_t stream) {
  (void)n_in; (void)out_size; (void)ws_size;
  const float* x   = (const float*)d_in[0];
  const float* et  = (const float*)d_in[1];
  const float* W1  = (const float*)d_in[2];
  const float* as1 = (const float*)d_in[3];
  const float* ad1 = (const float*)d_in[4];
  const float* b1  = (const float*)d_in[5];
  const float* W2  = (const float*)d_in[6];
  const float* as2 = (const float*)d_in[7];
  const float* ad2 = (const float*)d_in[8];
  const float* b2  = (const float*)d_in[9];
  const float* W3  = (const float*)d_in[10];
  const float* as3 = (const float*)d_in[11];
  const float* ad3 = (const float*)d_in[12];
  const float* b3  = (const float*)d_in[13];
  const float* tW1 = (const float*)d_in[14];
  const float* tb1 = (const float*)d_in[15];
  const float* tW2 = (const float*)d_in[16];
  const float* tb2 = (const float*)d_in[17];
  const float* fW1 = (const float*)d_in[18];
  const float* fb1 = (const float*)d_in[19];
  const float* fW2 = (const float*)d_in[20];
  const float* fb2 = (const float*)d_in[21];
  const float* lng = (const float*)d_in[22];
  const float* lnb = (const float*)d_in[23];
  const float* rW  = (const float*)d_in[24];
  const float* rb  = (const float*)d_in[25];
  const int*   ei  = (const int*)d_in[26];
  const int N = in_sizes[0] / 64;     // 20000
  const int E = in_sizes[26] / 2;     // 320000
  const int Mp = ((N + 127) / 128) * 128;  // 20096
  const int* src = ei;
  const int* dst = ei + E;

  char* cur = (char*)d_ws;
  auto carve = [&](size_t bytes) { char* p = cur; cur += (bytes + 255) & ~(size_t)255; return p; };
  __hip_bfloat16* xbf  = (__hip_bfloat16*)carve((size_t)Mp * 64 * 2);
  __hip_bfloat16* habf = (__hip_bfloat16*)carve((size_t)Mp * 512 * 2);
  __hip_bfloat16* xlbf = (__hip_bfloat16*)carve((size_t)Mp * 512 * 2);
  __hip_bfloat16* wt1  = (__hip_bfloat16*)carve((size_t)512 * 64 * 2);
  __hip_bfloat16* wt2  = (__hip_bfloat16*)carve((size_t)512 * 512 * 2);
  __hip_bfloat16* wt3  = (__hip_bfloat16*)carve((size_t)512 * 512 * 2);
  __hip_bfloat16* wtR  = (__hip_bfloat16*)carve((size_t)128 * 64 * 2);
  __hip_bfloat16* wtF1 = (__hip_bfloat16*)carve((size_t)128 * 128 * 2);
  __hip_bfloat16* wtF2 = (__hip_bfloat16*)carve((size_t)128 * 128 * 2);
  __hip_bfloat16* aggbf= (__hip_bfloat16*)carve((size_t)Mp * 128 * 2);
  __hip_bfloat16* z1bf = (__hip_bfloat16*)carve((size_t)Mp * 128 * 2);
  float* h3   = (float*)carve((size_t)N * 128 * 4);
  float* z2   = (float*)carve((size_t)N * 128 * 4);
  float* al   = (float*)carve((size_t)N * 4 * 4);
  float* ar   = (float*)carve((size_t)N * 4 * 4);
  float* tacc = (float*)carve(64 * 4);
  float* cvec = (float*)carve(128 * 4);
  int* cntD = (int*)carve((size_t)N * 4);
  int* offD = (int*)carve((size_t)(N + 1) * 4);
  int* curD = (int*)carve((size_t)N * 4);
  int* lstD = (int*)carve((size_t)E * 4);
  int* cntS = (int*)carve((size_t)N * 4);
  int* offS = (int*)carve((size_t)(N + 1) * 4);
  int* curS = (int*)carve((size_t)N * 4);
  int* lstS = (int*)carve((size_t)E * 4);
  float* xres = (float*)d_out;

  // CSR build
  k_init<<<(N + 255) / 256, 256, 0, stream>>>(cntD, curD, cntS, curS, tacc, N);
  k_count<<<(E + 255) / 256, 256, 0, stream>>>(src, dst, E, cntD, cntS);
  k_scan<<<1, 1024, 0, stream>>>(cntD, offD, N);
  k_scan<<<1, 1024, 0, stream>>>(cntS, offS, N);
  k_fill<<<(E + 255) / 256, 256, 0, stream>>>(src, dst, E, offD, curD, lstD, offS, curS, lstS);

  // time path -> cvec
  k_time_reduce<<<80, 256, 0, stream>>>(et, tW1, tb1, tacc, E);
  k_time_combine<<<1, 128, 0, stream>>>(tacc, tW2, tb2, fW1, fb1, cvec, E);

  // conversions
  k_convX<<<(Mp * 64 + 255) / 256, 256, 0, stream>>>(x, xbf, N, Mp);
  k_padzero<<<Mp - N, 256, 0, stream>>>(habf, aggbf, z1bf, N, Mp);
  { dim3 g(64 / 32, 512 / 64);  k_convWt<<<g, 256, 0, stream>>>(W1, wt1, 64, 512); }
  { dim3 g(512 / 32, 512 / 64); k_convWt<<<g, 256, 0, stream>>>(W2, wt2, 512, 512); }
  { dim3 g(512 / 32, 512 / 64); k_convWt<<<g, 256, 0, stream>>>(W3, wt3, 512, 512); }
  { dim3 g(64 / 32, 128 / 64);  k_convWt<<<g, 256, 0, stream>>>(rW, wtR, 64, 128); }
  { dim3 g(128 / 32, 128 / 64); k_convWt<<<g, 256, 0, stream>>>(fW1, wtF1, 128, 128); }
  { dim3 g(128 / 32, 128 / 64); k_convWt<<<g, 256, 0, stream>>>(fW2, wtF2, 128, 128); }

  const int TB = Mp / 128;  // 157
  // x_res = x @ rW + rb -> d_out (f32)
  {
    dim3 g(TB, 1);
    gemm_bf16<<<g, 256, 0, stream>>>(xbf, wtR, xres, rb, N, 128, 64, 0, 0);
  }
  // layer 1
  {
    dim3 g(TB, 4);
    gemm_bf16<<<g, 256, 0, stream>>>(xbf, wt1, xlbf, nullptr, Mp, 512, 64, 0, 1);
  }
  k_alar<<<(N + 3) / 4, 256, 0, stream>>>(xlbf, as1, ad1, al, ar, N);
  k_gat_agg<<<N, 256, 0, stream>>>(xlbf, al, ar, offD, lstD, b1, habf, nullptr, 0);
  // layer 2
  {
    dim3 g(TB, 4);
    gemm_bf16<<<g, 256, 0, stream>>>(habf, wt2, xlbf, nullptr, Mp, 512, 512, 0, 1);
  }
  k_alar<<<(N + 3) / 4, 256, 0, stream>>>(xlbf, as2, ad2, al, ar, N);
  k_gat_agg<<<N, 256, 0, stream>>>(xlbf, al, ar, offD, lstD, b2, habf, nullptr, 0);
  // layer 3 (head-mean epilogue, f32 out)
  {
    dim3 g(TB, 4);
    gemm_bf16<<<g, 256, 0, stream>>>(habf, wt3, xlbf, nullptr, Mp, 512, 512, 0, 1);
  }
  k_alar<<<(N + 3) / 4, 256, 0, stream>>>(xlbf, as3, ad3, al, ar, N);
  k_gat_agg<<<N, 256, 0, stream>>>(xlbf, al, ar, offD, lstD, b3, nullptr, h3, 1);

  // agg = segment_sum(h3[dst], src) -> bf16
  k_aggsrc<<<N, 128, 0, stream>>>(h3, offS, lstS, aggbf);

  // z1 = relu(agg @ fW1[:128] + cvec) (bf16); z2 = z1 @ fW2 + fb2 (f32)
  {
    dim3 g(TB, 1);
    gemm_bf16<<<g, 256, 0, stream>>>(aggbf, wtF1, z1bf, cvec, Mp, 128, 128, 1, 1);
    gemm_bf16<<<g, 256, 0, stream>>>(z1bf, wtF2, z2, fb2, N, 128, 128, 0, 0);
  }

  // layernorm + residual -> d_out
  k_ln_res<<<N, 128, 0, stream>>>(z2, lng, lnb, xres);
}

// Round 4
// 495.603 us; speedup vs baseline: 2.1787x; 1.2046x over previous
//
#include <hip/hip_runtime.h>
#include <hip/hip_bf16.h>
#include <math.h>

typedef short bf16x8 __attribute__((ext_vector_type(8)));
typedef float f32x4 __attribute__((ext_vector_type(4)));

__device__ __forceinline__ float lrelu(float v) { return v > 0.f ? v : 0.2f * v; }

__device__ __forceinline__ void gload16(const void* g, void* l) {
  __builtin_amdgcn_global_load_lds(
      (const __attribute__((address_space(1))) void*)g,
      (__attribute__((address_space(3))) void*)l, 16, 0, 0);
}

__device__ __forceinline__ uint packbf(float v0, float v1) {
  __hip_bfloat16 h0 = __float2bfloat16(v0);
  __hip_bfloat16 h1 = __float2bfloat16(v1);
  return (uint)(*(unsigned short*)&h0) | ((uint)(*(unsigned short*)&h1) << 16);
}

// ---------------- degree count ----------------
__global__ void k_count(const int* __restrict__ src, const int* __restrict__ dst, int E,
                        int* cntD, int* cntS) {
  int e = blockIdx.x * blockDim.x + threadIdx.x;
  if (e < E) {
    atomicAdd(&cntD[dst[e]], 1);
    atomicAdd(&cntS[src[e]], 1);
  }
}

// ---------------- exclusive scans (block 0: D, block 1: S) ----------------
__global__ __launch_bounds__(1024) void k_scan2(const int* __restrict__ cntD, int* __restrict__ offD,
                                                const int* __restrict__ cntS, int* __restrict__ offS,
                                                int n) {
  const int* cnt = blockIdx.x ? cntS : cntD;
  int* off = blockIdx.x ? offS : offD;
  __shared__ int sums[1024];
  int t = threadIdx.x;
  int PT = (n + 1023) >> 10;
  int start = t * PT;
  int local = 0;
  for (int i = 0; i < PT; ++i) {
    int idx = start + i;
    if (idx < n) local += cnt[idx];
  }
  sums[t] = local;
  __syncthreads();
  for (int o = 1; o < 1024; o <<= 1) {
    int v = (t >= o) ? sums[t - o] : 0;
    __syncthreads();
    sums[t] += v;
    __syncthreads();
  }
  int run = sums[t] - local;
  for (int i = 0; i < PT; ++i) {
    int idx = start + i;
    if (idx < n) { off[idx] = run; run += cnt[idx]; }
  }
  if (t == 1023) off[n] = run;
}

// ---------------- fill CSR lists ----------------
__global__ void k_fill(const int* __restrict__ src, const int* __restrict__ dst, int E,
                       const int* __restrict__ offD, int* curD, int* lstD,
                       const int* __restrict__ offS, int* curS, int* lstS) {
  int e = blockIdx.x * blockDim.x + threadIdx.x;
  if (e < E) {
    int d = dst[e], s = src[e];
    int p = atomicAdd(&curD[d], 1);
    lstD[offD[d] + p] = s;
    int q = atomicAdd(&curS[s], 1);
    lstS[offS[s] + q] = d;
  }
}

// ---------------- time embedding: sum_e relu(t*w+b) per k (shfl broadcast) ----------------
__global__ __launch_bounds__(256) void k_time_reduce(const float* __restrict__ et,
    const float* __restrict__ tW1, const float* __restrict__ tb1,
    float* __restrict__ tacc, int E) {
  int t = threadIdx.x;
  int l = t & 63;
  float wk = tW1[l], bk = tb1[l];
  float acc = 0.f;
  int gw = (blockIdx.x * 256 + t) >> 6;
  int nw = gridDim.x * 4;
  for (int base = gw * 64; base < E; base += nw * 64) {
    int idx = base + l;
    float v = (idx < E) ? et[idx] : 0.f;
    int cnt = E - base; if (cnt > 64) cnt = 64;
    for (int j = 0; j < cnt; ++j) {
      float tv = __shfl(v, j);
      float u = tv * wk + bk;
      acc += fmaxf(u, 0.f);
    }
  }
  __shared__ float buf[256];
  buf[t] = acc;
  __syncthreads();
  if (t < 64) {
    float s = buf[t] + buf[t + 64] + buf[t + 128] + buf[t + 192];
    atomicAdd(&tacc[t], s);
  }
}

// ---------------- cvec = (mean @ tW2 + tb2) @ fW1[128:] + fb1 ----------------
__global__ __launch_bounds__(128) void k_time_combine(const float* __restrict__ tacc,
    const float* __restrict__ tW2, const float* __restrict__ tb2,
    const float* __restrict__ fW1, const float* __restrict__ fb1,
    float* __restrict__ cvec, int E) {
  __shared__ float tm[128];
  int t = threadIdx.x;
  float inv = 1.f / (float)E;
  float acc = tb2[t];
  for (int k = 0; k < 64; ++k) acc += (tacc[k] * inv) * tW2[k * 128 + t];
  tm[t] = acc;
  __syncthreads();
  float c = fb1[t];
  for (int k = 0; k < 128; ++k) c += tm[k] * fW1[(128 + k) * 128 + t];
  cvec[t] = c;
}

// ---------------- fused weight convert+transpose for all 6 matrices ----------------
struct ConvDesc { const float* W; __hip_bfloat16* Wt; int K; int Nw; int tstart; };
struct ConvArgs { ConvDesc d[6]; };

__global__ __launch_bounds__(256) void k_convAll(ConvArgs a) {
  __shared__ float tile[32][65];
  int bid = blockIdx.x;
  int m = 0;
#pragma unroll
  for (int i = 1; i < 6; ++i) if (bid >= a.d[i].tstart) m = i;
  const float* W = a.d[m].W;
  __hip_bfloat16* Wt = a.d[m].Wt;
  int K = a.d[m].K, Nw = a.d[m].Nw;
  int lt = bid - a.d[m].tstart;
  int ntn = Nw >> 6;
  int bk = (lt / ntn) * 32;
  int bn = (lt % ntn) * 64;
  int t = threadIdx.x;
  int rn = t & 63, rk = t >> 6;
#pragma unroll
  for (int i = 0; i < 8; ++i) {
    int k = rk + i * 4;
    tile[k][rn] = W[(size_t)(bk + k) * Nw + bn + rn];
  }
  __syncthreads();
  int wk2 = (t & 15) * 2;
  int wn = t >> 4;
  uint* Wo = (uint*)Wt;
#pragma unroll
  for (int i = 0; i < 4; ++i) {
    int n = wn + i * 16;
    uint p = packbf(tile[wk2][n], tile[wk2 + 1][n]);
    Wo[((size_t)(bn + n) * K + bk + wk2) >> 1] = p;
  }
}

// ---------------- x f32 [N][64] -> bf16 [Mp][64] zero-padded ----------------
__global__ void k_convX(const float* __restrict__ x, __hip_bfloat16* __restrict__ xb,
                        int N, int Mp) {
  int i = blockIdx.x * blockDim.x + threadIdx.x;
  if (i < Mp * 64) {
    int row = i >> 6;
    xb[i] = __float2bfloat16(row < N ? x[i] : 0.f);
  }
}

// ---------------- zero pad rows [N,Mp) ----------------
__global__ void k_padzero(__hip_bfloat16* habf, __hip_bfloat16* aggbf, int N, int Mp) {
  int row = N + blockIdx.x;
  int t = threadIdx.x;
  __hip_bfloat16 z = __float2bfloat16(0.f);
  habf[(size_t)row * 512 + t] = z;
  habf[(size_t)row * 512 + t + 256] = z;
  if (t < 128) aggbf[(size_t)row * 128 + t] = z;
}

// ---------------- bf16 MFMA GEMM: C[Mp,Nw] = A[Mp,K] @ Bt[Nw,K]^T ----------------
__global__ __launch_bounds__(256) void gemm_bf16(
    const __hip_bfloat16* __restrict__ A, const __hip_bfloat16* __restrict__ Bt,
    void* __restrict__ Cout, const float* __restrict__ bias,
    int M, int Nw, int K, int relu, int outBf)
{
  __shared__ short As[128 * 32];
  __shared__ short Bs[128 * 32];
  int tid = threadIdx.x;
  int bm = blockIdx.x * 128;
  int bn = blockIdx.y * 128;
  int w = tid >> 6, l = tid & 63;
  int wr = (w >> 1) * 64, wc = (w & 1) * 64;
  f32x4 acc[4][4] = {};
  const short* Ag = (const short*)A;
  const short* Bg = (const short*)Bt;

  for (int k0 = 0; k0 < K; k0 += 32) {
#pragma unroll
    for (int i = 0; i < 2; ++i) {
      int slot = i * 256 + tid;
      int row = slot >> 2;
      int col = (slot & 3) * 8;
      gload16(Ag + (size_t)(bm + row) * K + k0 + col, &As[slot * 8]);
      gload16(Bg + (size_t)(bn + row) * K + k0 + col, &Bs[slot * 8]);
    }
    __syncthreads();
    bf16x8 af[4], bfr[4];
#pragma unroll
    for (int m = 0; m < 4; ++m)
      af[m] = *(const bf16x8*)&As[(wr + m * 16 + (l & 15)) * 32 + (l >> 4) * 8];
#pragma unroll
    for (int n = 0; n < 4; ++n)
      bfr[n] = *(const bf16x8*)&Bs[(wc + n * 16 + (l & 15)) * 32 + (l >> 4) * 8];
#pragma unroll
    for (int m = 0; m < 4; ++m)
#pragma unroll
      for (int n = 0; n < 4; ++n)
        acc[m][n] = __builtin_amdgcn_mfma_f32_16x16x32_bf16(af[m], bfr[n], acc[m][n], 0, 0, 0);
    __syncthreads();
  }

  int cr = (l >> 4) * 4;
  int cc = l & 15;
#pragma unroll
  for (int n = 0; n < 4; ++n) {
    int col = bn + wc + n * 16 + cc;
    float bb = bias ? bias[col] : 0.f;
#pragma unroll
    for (int m = 0; m < 4; ++m) {
      int gmb = bm + wr + m * 16 + cr;
#pragma unroll
      for (int r = 0; r < 4; ++r) {
        int gm = gmb + r;
        if (gm < M) {
          float v = acc[m][n][r] + bb;
          if (relu) v = fmaxf(v, 0.f);
          if (outBf) ((__hip_bfloat16*)Cout)[(size_t)gm * Nw + col] = __float2bfloat16(v);
          else ((float*)Cout)[(size_t)gm * Nw + col] = v;
        }
      }
    }
  }
}

// ---------------- per-node attention dots (wave per node, bf16x8 loads) ----------------
__global__ __launch_bounds__(256) void k_alar(const __hip_bfloat16* __restrict__ xl,
    const float* __restrict__ asrc, const float* __restrict__ adst,
    float* __restrict__ al, float* __restrict__ ar, int N) {
  int w = threadIdx.x >> 6, l = threadIdx.x & 63;
  int n = blockIdx.x * 4 + w;
  if (n >= N) return;
  bf16x8 xv = *(const bf16x8*)((const short*)xl + (size_t)n * 512 + l * 8);
  float4 a0 = *(const float4*)(asrc + l * 8);
  float4 a1 = *(const float4*)(asrc + l * 8 + 4);
  float4 d0 = *(const float4*)(adst + l * 8);
  float4 d1 = *(const float4*)(adst + l * 8 + 4);
  float xs[8];
#pragma unroll
  for (int j = 0; j < 8; ++j)
    xs[j] = __uint_as_float(((uint)(unsigned short)xv[j]) << 16);
  float s1 = xs[0]*a0.x + xs[1]*a0.y + xs[2]*a0.z + xs[3]*a0.w
           + xs[4]*a1.x + xs[5]*a1.y + xs[6]*a1.z + xs[7]*a1.w;
  float s2 = xs[0]*d0.x + xs[1]*d0.y + xs[2]*d0.z + xs[3]*d0.w
           + xs[4]*d1.x + xs[5]*d1.y + xs[6]*d1.z + xs[7]*d1.w;
#pragma unroll
  for (int o = 1; o < 16; o <<= 1) {
    s1 += __shfl_xor(s1, o);
    s2 += __shfl_xor(s2, o);
  }
  if ((l & 15) == 0) {
    al[n * 4 + (l >> 4)] = s1;
    ar[n * 4 + (l >> 4)] = s2;
  }
}

// ---------------- GAT aggregation: wave per dst node ----------------
// Self-loop = virtual edge j==deg. No block barriers (waves independent).
// mode 0: outb[d] = bf16(relu(agg512 + bias512))
// mode 1: outh[d] = bf16(relu(mean_heads(agg512) + bias128))
__global__ __launch_bounds__(256) void k_gat_agg(
    const __hip_bfloat16* __restrict__ xl, const float* __restrict__ al,
    const float* __restrict__ ar, const int* __restrict__ off,
    const int* __restrict__ lst, const float* __restrict__ bias,
    __hip_bfloat16* __restrict__ outb, __hip_bfloat16* __restrict__ outh,
    int mode, int N)
{
  __shared__ int   sside[4][64];
  __shared__ float sebuf[4][4][68];
  int w = threadIdx.x >> 6, l = threadIdx.x & 63;
  int d = blockIdx.x * 4 + w;
  bool active = (d < N);
  int base = 0, deg = 0, tot = 0;
  float4 arv = make_float4(0.f, 0.f, 0.f, 0.f);
  if (active) {
    base = off[d]; deg = off[d + 1] - base; tot = deg + 1;
    arv = *(const float4*)(ar + 4 * d);
  }
  // pass A: per-head max (plain fmax reduce, no exp)
  float mx0 = -1e30f, mx1 = -1e30f, mx2 = -1e30f, mx3 = -1e30f;
  for (int j = l; j < tot; j += 64) {
    int sid = (j == deg) ? d : lst[base + j];
    float4 av = *(const float4*)(al + 4 * sid);
    mx0 = fmaxf(mx0, lrelu(av.x + arv.x));
    mx1 = fmaxf(mx1, lrelu(av.y + arv.y));
    mx2 = fmaxf(mx2, lrelu(av.z + arv.z));
    mx3 = fmaxf(mx3, lrelu(av.w + arv.w));
  }
#pragma unroll
  for (int o = 1; o < 64; o <<= 1) {
    mx0 = fmaxf(mx0, __shfl_xor(mx0, o));
    mx1 = fmaxf(mx1, __shfl_xor(mx1, o));
    mx2 = fmaxf(mx2, __shfl_xor(mx2, o));
    mx3 = fmaxf(mx3, __shfl_xor(mx3, o));
  }
  int hh = l >> 4;
  float facc[8] = {0.f, 0.f, 0.f, 0.f, 0.f, 0.f, 0.f, 0.f};
  float dn0 = 0.f, dn1 = 0.f, dn2 = 0.f, dn3 = 0.f;
  const uint4* xw = (const uint4*)xl;
  // pass B: chunk of 64 edges -> (sid, e) in LDS, then full-row gather
  for (int cb = 0; cb < tot; cb += 64) {
    int j = cb + l;
    float e0 = 0.f, e1 = 0.f, e2 = 0.f, e3 = 0.f;
    int sid = 0;
    if (j < tot) {
      sid = (j == deg) ? d : lst[base + j];
      float4 av = *(const float4*)(al + 4 * sid);
      e0 = __expf(lrelu(av.x + arv.x) - mx0);
      e1 = __expf(lrelu(av.y + arv.y) - mx1);
      e2 = __expf(lrelu(av.z + arv.z) - mx2);
      e3 = __expf(lrelu(av.w + arv.w) - mx3);
      dn0 += e0; dn1 += e1; dn2 += e2; dn3 += e3;
    }
    sside[w][l] = sid;
    sebuf[w][0][l] = e0; sebuf[w][1][l] = e1;
    sebuf[w][2][l] = e2; sebuf[w][3][l] = e3;
    __threadfence_block();
    int cnt = tot - cb; if (cnt > 64) cnt = 64;
    for (int jj = 0; jj < cnt; ++jj) {
      int sid2 = sside[w][jj];
      float e = sebuf[w][hh][jj];
      uint4 pv = xw[(size_t)sid2 * 64 + l];
      facc[0] += e * __uint_as_float(pv.x << 16);
      facc[1] += e * __uint_as_float(pv.x & 0xffff0000u);
      facc[2] += e * __uint_as_float(pv.y << 16);
      facc[3] += e * __uint_as_float(pv.y & 0xffff0000u);
      facc[4] += e * __uint_as_float(pv.z << 16);
      facc[5] += e * __uint_as_float(pv.z & 0xffff0000u);
      facc[6] += e * __uint_as_float(pv.w << 16);
      facc[7] += e * __uint_as_float(pv.w & 0xffff0000u);
    }
    __threadfence_block();
  }
  // denom reduce across lanes
#pragma unroll
  for (int o = 1; o < 64; o <<= 1) {
    dn0 += __shfl_xor(dn0, o); dn1 += __shfl_xor(dn1, o);
    dn2 += __shfl_xor(dn2, o); dn3 += __shfl_xor(dn3, o);
  }
  if (!active) return;
  float dsel = hh == 0 ? dn0 : hh == 1 ? dn1 : hh == 2 ? dn2 : dn3;
  float rden = 1.f / dsel;
  if (mode == 0) {
    int c8 = l * 8;
    const float4* bp = (const float4*)(bias + c8);
    float4 b0 = bp[0], b1 = bp[1];
    float vb[8] = {b0.x, b0.y, b0.z, b0.w, b1.x, b1.y, b1.z, b1.w};
    uint4 o4; uint* po = (uint*)&o4;
#pragma unroll
    for (int i = 0; i < 4; ++i) {
      float v0 = fmaxf(facc[2*i]   * rden + vb[2*i],   0.f);
      float v1 = fmaxf(facc[2*i+1] * rden + vb[2*i+1], 0.f);
      po[i] = packbf(v0, v1);
    }
    ((uint4*)outb)[(size_t)d * 64 + l] = o4;
  } else {
#pragma unroll
    for (int i = 0; i < 8; ++i) {
      facc[i] *= rden;
      facc[i] += __shfl_xor(facc[i], 16);
      facc[i] += __shfl_xor(facc[i], 32);
    }
    if (l < 16) {
      int c = l * 8;
      const float4* bp = (const float4*)(bias + c);
      float4 b0 = bp[0], b1 = bp[1];
      float vb[8] = {b0.x, b0.y, b0.z, b0.w, b1.x, b1.y, b1.z, b1.w};
      uint4 o4; uint* po = (uint*)&o4;
#pragma unroll
      for (int i = 0; i < 4; ++i) {
        float v0 = fmaxf(facc[2*i]   * 0.25f + vb[2*i],   0.f);
        float v1 = fmaxf(facc[2*i+1] * 0.25f + vb[2*i+1], 0.f);
        po[i] = packbf(v0, v1);
      }
      ((uint4*)outh)[(size_t)d * 16 + l] = o4;
    }
  }
}

// ---------------- final src-side segment sum (h3 bf16 -> aggbf bf16) ----------------
__global__ __launch_bounds__(256) void k_aggsrc(const __hip_bfloat16* __restrict__ h3,
    const int* __restrict__ off, const int* __restrict__ lst,
    __hip_bfloat16* __restrict__ out, int N) {
  int w = threadIdx.x >> 6, l = threadIdx.x & 63;
  int n = blockIdx.x * 4 + w;
  if (n >= N) return;
  const uint* hw = (const uint*)h3;
  uint pv = hw[(size_t)n * 64 + l];
  float a0 = __uint_as_float(pv << 16);
  float a1 = __uint_as_float(pv & 0xffff0000u);
  int b = off[n], e = off[n + 1];
  for (int j = b; j < e; ++j) {
    int s = lst[j];
    uint q = hw[(size_t)s * 64 + l];
    a0 += __uint_as_float(q << 16);
    a1 += __uint_as_float(q & 0xffff0000u);
  }
  ((uint*)out)[(size_t)n * 64 + l] = packbf(a0, a1);
}

// ---------------- layernorm + residual (out holds x_res, overwritten) ----------------
__global__ __launch_bounds__(128) void k_ln_res(const float* __restrict__ z,
    const float* __restrict__ g, const float* __restrict__ bt, float* __restrict__ out) {
  int n = blockIdx.x, t = threadIdx.x;
  float v = z[(size_t)n * 128 + t];
  __shared__ float red[2];
  float s = v;
#pragma unroll
  for (int o = 32; o; o >>= 1) s += __shfl_down(s, o);
  if ((t & 63) == 0) red[t >> 6] = s;
  __syncthreads();
  float mu = (red[0] + red[1]) * (1.f / 128.f);
  float dv = v - mu;
  float q = dv * dv;
  __syncthreads();
#pragma unroll
  for (int o = 32; o; o >>= 1) q += __shfl_down(q, o);
  if ((t & 63) == 0) red[t >> 6] = q;
  __syncthreads();
  float var = (red[0] + red[1]) * (1.f / 128.f);
  float y = dv * rsqrtf(var + 1e-5f) * g[t] + bt[t];
  out[(size_t)n * 128 + t] = y + out[(size_t)n * 128 + t];
}

extern "C" void kernel_launch(void* const* d_in, const int* in_sizes, int n_in,
                              void* d_out, int out_size, void* d_ws, size_t ws_size,
                              hipStream_t stream) {
  (void)n_in; (void)out_size; (void)ws_size;
  const float* x   = (const float*)d_in[0];
  const float* et  = (const float*)d_in[1];
  const float* W1  = (const float*)d_in[2];
  const float* as1 = (const float*)d_in[3];
  const float* ad1 = (const float*)d_in[4];
  const float* b1  = (const float*)d_in[5];
  const float* W2  = (const float*)d_in[6];
  const float* as2 = (const float*)d_in[7];
  const float* ad2 = (const float*)d_in[8];
  const float* b2  = (const float*)d_in[9];
  const float* W3  = (const float*)d_in[10];
  const float* as3 = (const float*)d_in[11];
  const float* ad3 = (const float*)d_in[12];
  const float* b3  = (const float*)d_in[13];
  const float* tW1 = (const float*)d_in[14];
  const float* tb1 = (const float*)d_in[15];
  const float* tW2 = (const float*)d_in[16];
  const float* tb2 = (const float*)d_in[17];
  const float* fW1 = (const float*)d_in[18];
  const float* fb1 = (const float*)d_in[19];
  const float* fW2 = (const float*)d_in[20];
  const float* fb2 = (const float*)d_in[21];
  const float* lng = (const float*)d_in[22];
  const float* lnb = (const float*)d_in[23];
  const float* rW  = (const float*)d_in[24];
  const float* rb  = (const float*)d_in[25];
  const int*   ei  = (const int*)d_in[26];
  const int N = in_sizes[0] / 64;     // 20000
  const int E = in_sizes[26] / 2;     // 320000
  const int Mp = ((N + 127) / 128) * 128;  // 20096
  const int* src = ei;
  const int* dst = ei + E;

  char* cur = (char*)d_ws;
  auto carve = [&](size_t bytes) { char* p = cur; cur += (bytes + 255) & ~(size_t)255; return p; };
  __hip_bfloat16* xbf  = (__hip_bfloat16*)carve((size_t)Mp * 64 * 2);
  __hip_bfloat16* habf = (__hip_bfloat16*)carve((size_t)Mp * 512 * 2);
  __hip_bfloat16* xlbf = (__hip_bfloat16*)carve((size_t)Mp * 512 * 2);
  __hip_bfloat16* wt1  = (__hip_bfloat16*)carve((size_t)512 * 64 * 2);
  __hip_bfloat16* wt2  = (__hip_bfloat16*)carve((size_t)512 * 512 * 2);
  __hip_bfloat16* wt3  = (__hip_bfloat16*)carve((size_t)512 * 512 * 2);
  __hip_bfloat16* wtR  = (__hip_bfloat16*)carve((size_t)128 * 64 * 2);
  __hip_bfloat16* wtF1 = (__hip_bfloat16*)carve((size_t)128 * 128 * 2);
  __hip_bfloat16* wtF2 = (__hip_bfloat16*)carve((size_t)128 * 128 * 2);
  __hip_bfloat16* aggbf= (__hip_bfloat16*)carve((size_t)Mp * 128 * 2);
  __hip_bfloat16* z1bf = (__hip_bfloat16*)carve((size_t)Mp * 128 * 2);
  __hip_bfloat16* h3   = (__hip_bfloat16*)carve((size_t)N * 128 * 2);
  float* z2   = (float*)carve((size_t)N * 128 * 4);
  float* al   = (float*)carve((size_t)N * 4 * 4);
  float* ar   = (float*)carve((size_t)N * 4 * 4);
  float* cvec = (float*)carve(128 * 4);
  int* offD = (int*)carve((size_t)(N + 1) * 4);
  int* offS = (int*)carve((size_t)(N + 1) * 4);
  int* lstD = (int*)carve((size_t)E * 4);
  int* lstS = (int*)carve((size_t)E * 4);
  // zeroed region (one memset): cntD, curD, cntS, curS, tacc
  char* zstart = cur;
  int* cntD = (int*)carve((size_t)N * 4);
  int* curD = (int*)carve((size_t)N * 4);
  int* cntS = (int*)carve((size_t)N * 4);
  int* curS = (int*)carve((size_t)N * 4);
  float* tacc = (float*)carve(64 * 4);
  size_t zbytes = (size_t)(cur - zstart);
  float* xres = (float*)d_out;

  hipMemsetAsync(zstart, 0, zbytes, stream);

  // CSR build
  k_count<<<(E + 255) / 256, 256, 0, stream>>>(src, dst, E, cntD, cntS);
  k_scan2<<<2, 1024, 0, stream>>>(cntD, offD, cntS, offS, N);
  k_fill<<<(E + 255) / 256, 256, 0, stream>>>(src, dst, E, offD, curD, lstD, offS, curS, lstS);

  // time path -> cvec
  k_time_reduce<<<80, 256, 0, stream>>>(et, tW1, tb1, tacc, E);
  k_time_combine<<<1, 128, 0, stream>>>(tacc, tW2, tb2, fW1, fb1, cvec, E);

  // conversions
  k_convX<<<(Mp * 64 + 255) / 256, 256, 0, stream>>>(x, xbf, N, Mp);
  k_padzero<<<Mp - N, 256, 0, stream>>>(habf, aggbf, N, Mp);
  {
    ConvArgs ca;
    int ts = 0;
    auto setd = [&](int i, const float* W, __hip_bfloat16* Wt, int K, int Nw) {
      ca.d[i] = ConvDesc{W, Wt, K, Nw, ts};
      ts += (K / 32) * (Nw / 64);
    };
    setd(0, W1, wt1, 64, 512);
    setd(1, W2, wt2, 512, 512);
    setd(2, W3, wt3, 512, 512);
    setd(3, rW, wtR, 64, 128);
    setd(4, fW1, wtF1, 128, 128);
    setd(5, fW2, wtF2, 128, 128);
    k_convAll<<<ts, 256, 0, stream>>>(ca);
  }

  const int TB = Mp / 128;  // 157
  const int GB = (N + 3) / 4;
  // x_res = x @ rW + rb -> d_out (f32)
  { dim3 g(TB, 1); gemm_bf16<<<g, 256, 0, stream>>>(xbf, wtR, xres, rb, N, 128, 64, 0, 0); }
  // layer 1
  { dim3 g(TB, 4); gemm_bf16<<<g, 256, 0, stream>>>(xbf, wt1, xlbf, nullptr, Mp, 512, 64, 0, 1); }
  k_alar<<<GB, 256, 0, stream>>>(xlbf, as1, ad1, al, ar, N);
  k_gat_agg<<<GB, 256, 0, stream>>>(xlbf, al, ar, offD, lstD, b1, habf, nullptr, 0, N);
  // layer 2
  { dim3 g(TB, 4); gemm_bf16<<<g, 256, 0, stream>>>(habf, wt2, xlbf, nullptr, Mp, 512, 512, 0, 1); }
  k_alar<<<GB, 256, 0, stream>>>(xlbf, as2, ad2, al, ar, N);
  k_gat_agg<<<GB, 256, 0, stream>>>(xlbf, al, ar, offD, lstD, b2, habf, nullptr, 0, N);
  // layer 3 (head-mean epilogue -> h3 bf16)
  { dim3 g(TB, 4); gemm_bf16<<<g, 256, 0, stream>>>(habf, wt3, xlbf, nullptr, Mp, 512, 512, 0, 1); }
  k_alar<<<GB, 256, 0, stream>>>(xlbf, as3, ad3, al, ar, N);
  k_gat_agg<<<GB, 256, 0, stream>>>(xlbf, al, ar, offD, lstD, b3, nullptr, h3, 1, N);

  // agg = segment_sum(h3[dst], src) -> bf16
  k_aggsrc<<<GB, 256, 0, stream>>>(h3, offS, lstS, aggbf, N);

  // z1 = relu(agg @ fW1[:128] + cvec) (bf16); z2 = z1 @ fW2 + fb2 (f32)
  {
    dim3 g(TB, 1);
    gemm_bf16<<<g, 256, 0, stream>>>(aggbf, wtF1, z1bf, cvec, Mp, 128, 128, 1, 1);
    gemm_bf16<<<g, 256, 0, stream>>>(z1bf, wtF2, z2, fb2, N, 128, 128, 0, 0);
  }

  // layernorm + residual -> d_out
  k_ln_res<<<N, 128, 0, stream>>>(z2, lng, lnb, xres);
}

// Round 5
// 446.484 us; speedup vs baseline: 2.4184x; 1.1100x over previous
//
#include <hip/hip_runtime.h>
#include <hip/hip_bf16.h>
#include <math.h>

typedef short bf16x8 __attribute__((ext_vector_type(8)));
typedef float f32x4 __attribute__((ext_vector_type(4)));

__device__ __forceinline__ float lrelu(float v) { return v > 0.f ? v : 0.2f * v; }

__device__ __forceinline__ void gload16(const void* g, void* l) {
  __builtin_amdgcn_global_load_lds(
      (const __attribute__((address_space(1))) void*)g,
      (__attribute__((address_space(3))) void*)l, 16, 0, 0);
}

__device__ __forceinline__ uint packbf(float v0, float v1) {
  __hip_bfloat16 h0 = __float2bfloat16(v0);
  __hip_bfloat16 h1 = __float2bfloat16(v1);
  return (uint)(*(unsigned short*)&h0) | ((uint)(*(unsigned short*)&h1) << 16);
}

// ---------------- degree count ----------------
__global__ void k_count(const int* __restrict__ src, const int* __restrict__ dst, int E,
                        int* cntD, int* cntS) {
  int e = blockIdx.x * blockDim.x + threadIdx.x;
  if (e < E) {
    atomicAdd(&cntD[dst[e]], 1);
    atomicAdd(&cntS[src[e]], 1);
  }
}

// ---------------- exclusive scans (block 0: D, block 1: S) ----------------
__global__ __launch_bounds__(1024) void k_scan2(const int* __restrict__ cntD, int* __restrict__ offD,
                                                const int* __restrict__ cntS, int* __restrict__ offS,
                                                int n) {
  const int* cnt = blockIdx.x ? cntS : cntD;
  int* off = blockIdx.x ? offS : offD;
  __shared__ int sums[1024];
  int t = threadIdx.x;
  int PT = (n + 1023) >> 10;
  int start = t * PT;
  int local = 0;
  for (int i = 0; i < PT; ++i) {
    int idx = start + i;
    if (idx < n) local += cnt[idx];
  }
  sums[t] = local;
  __syncthreads();
  for (int o = 1; o < 1024; o <<= 1) {
    int v = (t >= o) ? sums[t - o] : 0;
    __syncthreads();
    sums[t] += v;
    __syncthreads();
  }
  int run = sums[t] - local;
  for (int i = 0; i < PT; ++i) {
    int idx = start + i;
    if (idx < n) { off[idx] = run; run += cnt[idx]; }
  }
  if (t == 1023) off[n] = run;
}

// ---------------- fill CSR lists ----------------
__global__ void k_fill(const int* __restrict__ src, const int* __restrict__ dst, int E,
                       const int* __restrict__ offD, int* curD, int* lstD,
                       const int* __restrict__ offS, int* curS, int* lstS) {
  int e = blockIdx.x * blockDim.x + threadIdx.x;
  if (e < E) {
    int d = dst[e], s = src[e];
    int p = atomicAdd(&curD[d], 1);
    lstD[offD[d] + p] = s;
    int q = atomicAdd(&curS[s], 1);
    lstS[offS[s] + q] = d;
  }
}

// ---------------- time embedding: LDS tile + uniform broadcast reads ----------------
__global__ __launch_bounds__(256) void k_time_reduce(const float* __restrict__ et,
    const float* __restrict__ tW1, const float* __restrict__ tb1,
    float* __restrict__ tacc, int E) {
  __shared__ float se[256];
  __shared__ float buf[256];
  int t = threadIdx.x;
  int l = t & 63, w = t >> 6;
  float wk = tW1[l], bk = tb1[l];
  float a0 = 0.f, a1 = 0.f, a2 = 0.f, a3 = 0.f;
  for (int base = blockIdx.x * 256; base < E; base += gridDim.x * 256) {
    int idx = base + t;
    se[t] = (idx < E) ? et[idx] : 0.f;
    __syncthreads();
    int cnt = E - base; if (cnt > 256) cnt = 256;
    int s0 = w * 64;
    int c = cnt - s0; if (c < 0) c = 0; if (c > 64) c = 64;
    int j = 0;
    for (; j + 4 <= c; j += 4) {
      float v0 = se[s0 + j], v1 = se[s0 + j + 1];
      float v2 = se[s0 + j + 2], v3 = se[s0 + j + 3];
      a0 += fmaxf(v0 * wk + bk, 0.f);
      a1 += fmaxf(v1 * wk + bk, 0.f);
      a2 += fmaxf(v2 * wk + bk, 0.f);
      a3 += fmaxf(v3 * wk + bk, 0.f);
    }
    for (; j < c; ++j) a0 += fmaxf(se[s0 + j] * wk + bk, 0.f);
    __syncthreads();
  }
  buf[t] = (a0 + a1) + (a2 + a3);
  __syncthreads();
  if (t < 64) {
    float s = buf[t] + buf[t + 64] + buf[t + 128] + buf[t + 192];
    atomicAdd(&tacc[t], s);
  }
}

// ---------------- cvec = (mean @ tW2 + tb2) @ fW1[128:] + fb1 ----------------
__global__ __launch_bounds__(128) void k_time_combine(const float* __restrict__ tacc,
    const float* __restrict__ tW2, const float* __restrict__ tb2,
    const float* __restrict__ fW1, const float* __restrict__ fb1,
    float* __restrict__ cvec, int E) {
  __shared__ float tm[128];
  int t = threadIdx.x;
  float inv = 1.f / (float)E;
  float acc = tb2[t];
  for (int k = 0; k < 64; ++k) acc += (tacc[k] * inv) * tW2[k * 128 + t];
  tm[t] = acc;
  __syncthreads();
  float c = fb1[t];
  for (int k = 0; k < 128; ++k) c += tm[k] * fW1[(128 + k) * 128 + t];
  cvec[t] = c;
}

// ---------------- fused weight convert+transpose for all 6 matrices ----------------
struct ConvDesc { const float* W; __hip_bfloat16* Wt; int K; int Nw; int tstart; };
struct ConvArgs { ConvDesc d[6]; };

__global__ __launch_bounds__(256) void k_convAll(ConvArgs a) {
  __shared__ float tile[32][65];
  int bid = blockIdx.x;
  int m = 0;
#pragma unroll
  for (int i = 1; i < 6; ++i) if (bid >= a.d[i].tstart) m = i;
  const float* W = a.d[m].W;
  __hip_bfloat16* Wt = a.d[m].Wt;
  int K = a.d[m].K, Nw = a.d[m].Nw;
  int lt = bid - a.d[m].tstart;
  int ntn = Nw >> 6;
  int bk = (lt / ntn) * 32;
  int bn = (lt % ntn) * 64;
  int t = threadIdx.x;
  int rn = t & 63, rk = t >> 6;
#pragma unroll
  for (int i = 0; i < 8; ++i) {
    int k = rk + i * 4;
    tile[k][rn] = W[(size_t)(bk + k) * Nw + bn + rn];
  }
  __syncthreads();
  int wk2 = (t & 15) * 2;
  int wn = t >> 4;
  uint* Wo = (uint*)Wt;
#pragma unroll
  for (int i = 0; i < 4; ++i) {
    int n = wn + i * 16;
    uint p = packbf(tile[wk2][n], tile[wk2 + 1][n]);
    Wo[((size_t)(bn + n) * K + bk + wk2) >> 1] = p;
  }
}

// ---------------- x f32 [N][64] -> bf16 [Mp][64] zero-padded ----------------
__global__ void k_convX(const float* __restrict__ x, __hip_bfloat16* __restrict__ xb,
                        int N, int Mp) {
  int i = blockIdx.x * blockDim.x + threadIdx.x;
  if (i < Mp * 64) {
    int row = i >> 6;
    xb[i] = __float2bfloat16(row < N ? x[i] : 0.f);
  }
}

// ---------------- zero pad rows [N,Mp) ----------------
__global__ void k_padzero(__hip_bfloat16* habf, __hip_bfloat16* aggbf, int N, int Mp) {
  int row = N + blockIdx.x;
  int t = threadIdx.x;
  __hip_bfloat16 z = __float2bfloat16(0.f);
  habf[(size_t)row * 512 + t] = z;
  habf[(size_t)row * 512 + t + 256] = z;
  if (t < 128) aggbf[(size_t)row * 128 + t] = z;
}

// ---------------- bf16 MFMA GEMM: C[Mp,Nw] = A[Mp,K] @ Bt[Nw,K]^T ----------------
__global__ __launch_bounds__(256) void gemm_bf16(
    const __hip_bfloat16* __restrict__ A, const __hip_bfloat16* __restrict__ Bt,
    void* __restrict__ Cout, const float* __restrict__ bias,
    int M, int Nw, int K, int relu, int outBf)
{
  __shared__ short As[128 * 32];
  __shared__ short Bs[128 * 32];
  int tid = threadIdx.x;
  int bm = blockIdx.x * 128;
  int bn = blockIdx.y * 128;
  int w = tid >> 6, l = tid & 63;
  int wr = (w >> 1) * 64, wc = (w & 1) * 64;
  f32x4 acc[4][4] = {};
  const short* Ag = (const short*)A;
  const short* Bg = (const short*)Bt;

  for (int k0 = 0; k0 < K; k0 += 32) {
#pragma unroll
    for (int i = 0; i < 2; ++i) {
      int slot = i * 256 + tid;
      int row = slot >> 2;
      int col = (slot & 3) * 8;
      gload16(Ag + (size_t)(bm + row) * K + k0 + col, &As[slot * 8]);
      gload16(Bg + (size_t)(bn + row) * K + k0 + col, &Bs[slot * 8]);
    }
    __syncthreads();
    bf16x8 af[4], bfr[4];
#pragma unroll
    for (int m = 0; m < 4; ++m)
      af[m] = *(const bf16x8*)&As[(wr + m * 16 + (l & 15)) * 32 + (l >> 4) * 8];
#pragma unroll
    for (int n = 0; n < 4; ++n)
      bfr[n] = *(const bf16x8*)&Bs[(wc + n * 16 + (l & 15)) * 32 + (l >> 4) * 8];
#pragma unroll
    for (int m = 0; m < 4; ++m)
#pragma unroll
      for (int n = 0; n < 4; ++n)
        acc[m][n] = __builtin_amdgcn_mfma_f32_16x16x32_bf16(af[m], bfr[n], acc[m][n], 0, 0, 0);
    __syncthreads();
  }

  int cr = (l >> 4) * 4;
  int cc = l & 15;
#pragma unroll
  for (int n = 0; n < 4; ++n) {
    int col = bn + wc + n * 16 + cc;
    float bb = bias ? bias[col] : 0.f;
#pragma unroll
    for (int m = 0; m < 4; ++m) {
      int gmb = bm + wr + m * 16 + cr;
#pragma unroll
      for (int r = 0; r < 4; ++r) {
        int gm = gmb + r;
        if (gm < M) {
          float v = acc[m][n][r] + bb;
          if (relu) v = fmaxf(v, 0.f);
          if (outBf) ((__hip_bfloat16*)Cout)[(size_t)gm * Nw + col] = __float2bfloat16(v);
          else ((float*)Cout)[(size_t)gm * Nw + col] = v;
        }
      }
    }
  }
}

// ---------------- per-node attention dots (wave per node, bf16x8 loads) ----------------
__global__ __launch_bounds__(256) void k_alar(const __hip_bfloat16* __restrict__ xl,
    const float* __restrict__ asrc, const float* __restrict__ adst,
    float* __restrict__ al, float* __restrict__ ar, int N) {
  int w = threadIdx.x >> 6, l = threadIdx.x & 63;
  int n = blockIdx.x * 4 + w;
  if (n >= N) return;
  bf16x8 xv = *(const bf16x8*)((const short*)xl + (size_t)n * 512 + l * 8);
  float4 a0 = *(const float4*)(asrc + l * 8);
  float4 a1 = *(const float4*)(asrc + l * 8 + 4);
  float4 d0 = *(const float4*)(adst + l * 8);
  float4 d1 = *(const float4*)(adst + l * 8 + 4);
  float xs[8];
#pragma unroll
  for (int j = 0; j < 8; ++j)
    xs[j] = __uint_as_float(((uint)(unsigned short)xv[j]) << 16);
  float s1 = xs[0]*a0.x + xs[1]*a0.y + xs[2]*a0.z + xs[3]*a0.w
           + xs[4]*a1.x + xs[5]*a1.y + xs[6]*a1.z + xs[7]*a1.w;
  float s2 = xs[0]*d0.x + xs[1]*d0.y + xs[2]*d0.z + xs[3]*d0.w
           + xs[4]*d1.x + xs[5]*d1.y + xs[6]*d1.z + xs[7]*d1.w;
#pragma unroll
  for (int o = 1; o < 16; o <<= 1) {
    s1 += __shfl_xor(s1, o);
    s2 += __shfl_xor(s2, o);
  }
  if ((l & 15) == 0) {
    al[n * 4 + (l >> 4)] = s1;
    ar[n * 4 + (l >> 4)] = s2;
  }
}

// ---------------- GAT aggregation: wave per dst node ----------------
__global__ __launch_bounds__(256) void k_gat_agg(
    const __hip_bfloat16* __restrict__ xl, const float* __restrict__ al,
    const float* __restrict__ ar, const int* __restrict__ off,
    const int* __restrict__ lst, const float* __restrict__ bias,
    __hip_bfloat16* __restrict__ outb, __hip_bfloat16* __restrict__ outh,
    int mode, int N)
{
  __shared__ int   sside[4][64];
  __shared__ float sebuf[4][4][68];
  int w = threadIdx.x >> 6, l = threadIdx.x & 63;
  int d = blockIdx.x * 4 + w;
  bool active = (d < N);
  int base = 0, deg = 0, tot = 0;
  float4 arv = make_float4(0.f, 0.f, 0.f, 0.f);
  if (active) {
    base = off[d]; deg = off[d + 1] - base; tot = deg + 1;
    arv = *(const float4*)(ar + 4 * d);
  }
  float mx0 = -1e30f, mx1 = -1e30f, mx2 = -1e30f, mx3 = -1e30f;
  for (int j = l; j < tot; j += 64) {
    int sid = (j == deg) ? d : lst[base + j];
    float4 av = *(const float4*)(al + 4 * sid);
    mx0 = fmaxf(mx0, lrelu(av.x + arv.x));
    mx1 = fmaxf(mx1, lrelu(av.y + arv.y));
    mx2 = fmaxf(mx2, lrelu(av.z + arv.z));
    mx3 = fmaxf(mx3, lrelu(av.w + arv.w));
  }
#pragma unroll
  for (int o = 1; o < 64; o <<= 1) {
    mx0 = fmaxf(mx0, __shfl_xor(mx0, o));
    mx1 = fmaxf(mx1, __shfl_xor(mx1, o));
    mx2 = fmaxf(mx2, __shfl_xor(mx2, o));
    mx3 = fmaxf(mx3, __shfl_xor(mx3, o));
  }
  int hh = l >> 4;
  float facc[8] = {0.f, 0.f, 0.f, 0.f, 0.f, 0.f, 0.f, 0.f};
  float dn0 = 0.f, dn1 = 0.f, dn2 = 0.f, dn3 = 0.f;
  const uint4* xw = (const uint4*)xl;
  for (int cb = 0; cb < tot; cb += 64) {
    int j = cb + l;
    float e0 = 0.f, e1 = 0.f, e2 = 0.f, e3 = 0.f;
    int sid = 0;
    if (j < tot) {
      sid = (j == deg) ? d : lst[base + j];
      float4 av = *(const float4*)(al + 4 * sid);
      e0 = __expf(lrelu(av.x + arv.x) - mx0);
      e1 = __expf(lrelu(av.y + arv.y) - mx1);
      e2 = __expf(lrelu(av.z + arv.z) - mx2);
      e3 = __expf(lrelu(av.w + arv.w) - mx3);
      dn0 += e0; dn1 += e1; dn2 += e2; dn3 += e3;
    }
    sside[w][l] = sid;
    sebuf[w][0][l] = e0; sebuf[w][1][l] = e1;
    sebuf[w][2][l] = e2; sebuf[w][3][l] = e3;
    int cnt = tot - cb; if (cnt > 64) cnt = 64;
    for (int jj = 0; jj < cnt; ++jj) {
      int sid2 = sside[w][jj];
      float e = sebuf[w][hh][jj];
      uint4 pv = xw[(size_t)sid2 * 64 + l];
      facc[0] += e * __uint_as_float(pv.x << 16);
      facc[1] += e * __uint_as_float(pv.x & 0xffff0000u);
      facc[2] += e * __uint_as_float(pv.y << 16);
      facc[3] += e * __uint_as_float(pv.y & 0xffff0000u);
      facc[4] += e * __uint_as_float(pv.z << 16);
      facc[5] += e * __uint_as_float(pv.z & 0xffff0000u);
      facc[6] += e * __uint_as_float(pv.w << 16);
      facc[7] += e * __uint_as_float(pv.w & 0xffff0000u);
    }
  }
#pragma unroll
  for (int o = 1; o < 64; o <<= 1) {
    dn0 += __shfl_xor(dn0, o); dn1 += __shfl_xor(dn1, o);
    dn2 += __shfl_xor(dn2, o); dn3 += __shfl_xor(dn3, o);
  }
  if (!active) return;
  float dsel = hh == 0 ? dn0 : hh == 1 ? dn1 : hh == 2 ? dn2 : dn3;
  float rden = 1.f / dsel;
  if (mode == 0) {
    int c8 = l * 8;
    const float4* bp = (const float4*)(bias + c8);
    float4 b0 = bp[0], b1 = bp[1];
    float vb[8] = {b0.x, b0.y, b0.z, b0.w, b1.x, b1.y, b1.z, b1.w};
    uint4 o4; uint* po = (uint*)&o4;
#pragma unroll
    for (int i = 0; i < 4; ++i) {
      float v0 = fmaxf(facc[2*i]   * rden + vb[2*i],   0.f);
      float v1 = fmaxf(facc[2*i+1] * rden + vb[2*i+1], 0.f);
      po[i] = packbf(v0, v1);
    }
    ((uint4*)outb)[(size_t)d * 64 + l] = o4;
  } else {
#pragma unroll
    for (int i = 0; i < 8; ++i) {
      facc[i] *= rden;
      facc[i] += __shfl_xor(facc[i], 16);
      facc[i] += __shfl_xor(facc[i], 32);
    }
    if (l < 16) {
      int c = l * 8;
      const float4* bp = (const float4*)(bias + c);
      float4 b0 = bp[0], b1 = bp[1];
      float vb[8] = {b0.x, b0.y, b0.z, b0.w, b1.x, b1.y, b1.z, b1.w};
      uint4 o4; uint* po = (uint*)&o4;
#pragma unroll
      for (int i = 0; i < 4; ++i) {
        float v0 = fmaxf(facc[2*i]   * 0.25f + vb[2*i],   0.f);
        float v1 = fmaxf(facc[2*i+1] * 0.25f + vb[2*i+1], 0.f);
        po[i] = packbf(v0, v1);
      }
      ((uint4*)outh)[(size_t)d * 16 + l] = o4;
    }
  }
}

// ---------------- final src-side segment sum (h3 bf16 -> aggbf bf16) ----------------
__global__ __launch_bounds__(256) void k_aggsrc(const __hip_bfloat16* __restrict__ h3,
    const int* __restrict__ off, const int* __restrict__ lst,
    __hip_bfloat16* __restrict__ out, int N) {
  int w = threadIdx.x >> 6, l = threadIdx.x & 63;
  int n = blockIdx.x * 4 + w;
  if (n >= N) return;
  const uint* hw = (const uint*)h3;
  uint pv = hw[(size_t)n * 64 + l];
  float a0 = __uint_as_float(pv << 16);
  float a1 = __uint_as_float(pv & 0xffff0000u);
  float b0 = 0.f, b1 = 0.f;
  int b = off[n], e = off[n + 1];
  int j = b;
  for (; j + 2 <= e; j += 2) {
    int s0 = lst[j], s1 = lst[j + 1];
    uint q0 = hw[(size_t)s0 * 64 + l];
    uint q1 = hw[(size_t)s1 * 64 + l];
    a0 += __uint_as_float(q0 << 16);
    a1 += __uint_as_float(q0 & 0xffff0000u);
    b0 += __uint_as_float(q1 << 16);
    b1 += __uint_as_float(q1 & 0xffff0000u);
  }
  if (j < e) {
    uint q = hw[(size_t)lst[j] * 64 + l];
    a0 += __uint_as_float(q << 16);
    a1 += __uint_as_float(q & 0xffff0000u);
  }
  ((uint*)out)[(size_t)n * 64 + l] = packbf(a0 + b0, a1 + b1);
}

// ---------------- layernorm + residual (out holds x_res, overwritten) ----------------
__global__ __launch_bounds__(128) void k_ln_res(const float* __restrict__ z,
    const float* __restrict__ g, const float* __restrict__ bt, float* __restrict__ out) {
  int n = blockIdx.x, t = threadIdx.x;
  float v = z[(size_t)n * 128 + t];
  __shared__ float red[2];
  float s = v;
#pragma unroll
  for (int o = 32; o; o >>= 1) s += __shfl_down(s, o);
  if ((t & 63) == 0) red[t >> 6] = s;
  __syncthreads();
  float mu = (red[0] + red[1]) * (1.f / 128.f);
  float dv = v - mu;
  float q = dv * dv;
  __syncthreads();
#pragma unroll
  for (int o = 32; o; o >>= 1) q += __shfl_down(q, o);
  if ((t & 63) == 0) red[t >> 6] = q;
  __syncthreads();
  float var = (red[0] + red[1]) * (1.f / 128.f);
  float y = dv * rsqrtf(var + 1e-5f) * g[t] + bt[t];
  out[(size_t)n * 128 + t] = y + out[(size_t)n * 128 + t];
}

extern "C" void kernel_launch(void* const* d_in, const int* in_sizes, int n_in,
                              void* d_out, int out_size, void* d_ws, size_t ws_size,
                              hipStream_t stream) {
  (void)n_in; (void)out_size; (void)ws_size;
  const float* x   = (const float*)d_in[0];
  const float* et  = (const float*)d_in[1];
  const float* W1  = (const float*)d_in[2];
  const float* as1 = (const float*)d_in[3];
  const float* ad1 = (const float*)d_in[4];
  const float* b1  = (const float*)d_in[5];
  const float* W2  = (const float*)d_in[6];
  const float* as2 = (const float*)d_in[7];
  const float* ad2 = (const float*)d_in[8];
  const float* b2  = (const float*)d_in[9];
  const float* W3  = (const float*)d_in[10];
  const float* as3 = (const float*)d_in[11];
  const float* ad3 = (const float*)d_in[12];
  const float* b3  = (const float*)d_in[13];
  const float* tW1 = (const float*)d_in[14];
  const float* tb1 = (const float*)d_in[15];
  const float* tW2 = (const float*)d_in[16];
  const float* tb2 = (const float*)d_in[17];
  const float* fW1 = (const float*)d_in[18];
  const float* fb1 = (const float*)d_in[19];
  const float* fW2 = (const float*)d_in[20];
  const float* fb2 = (const float*)d_in[21];
  const float* lng = (const float*)d_in[22];
  const float* lnb = (const float*)d_in[23];
  const float* rW  = (const float*)d_in[24];
  const float* rb  = (const float*)d_in[25];
  const int*   ei  = (const int*)d_in[26];
  const int N = in_sizes[0] / 64;     // 20000
  const int E = in_sizes[26] / 2;     // 320000
  const int Mp = ((N + 127) / 128) * 128;  // 20096
  const int* src = ei;
  const int* dst = ei + E;

  char* cur = (char*)d_ws;
  auto carve = [&](size_t bytes) { char* p = cur; cur += (bytes + 255) & ~(size_t)255; return p; };
  __hip_bfloat16* xbf  = (__hip_bfloat16*)carve((size_t)Mp * 64 * 2);
  __hip_bfloat16* habf = (__hip_bfloat16*)carve((size_t)Mp * 512 * 2);
  __hip_bfloat16* xlbf = (__hip_bfloat16*)carve((size_t)Mp * 512 * 2);
  __hip_bfloat16* wt1  = (__hip_bfloat16*)carve((size_t)512 * 64 * 2);
  __hip_bfloat16* wt2  = (__hip_bfloat16*)carve((size_t)512 * 512 * 2);
  __hip_bfloat16* wt3  = (__hip_bfloat16*)carve((size_t)512 * 512 * 2);
  __hip_bfloat16* wtR  = (__hip_bfloat16*)carve((size_t)128 * 64 * 2);
  __hip_bfloat16* wtF1 = (__hip_bfloat16*)carve((size_t)128 * 128 * 2);
  __hip_bfloat16* wtF2 = (__hip_bfloat16*)carve((size_t)128 * 128 * 2);
  __hip_bfloat16* aggbf= (__hip_bfloat16*)carve((size_t)Mp * 128 * 2);
  __hip_bfloat16* z1bf = (__hip_bfloat16*)carve((size_t)Mp * 128 * 2);
  __hip_bfloat16* h3   = (__hip_bfloat16*)carve((size_t)N * 128 * 2);
  float* z2   = (float*)carve((size_t)N * 128 * 4);
  float* al   = (float*)carve((size_t)N * 4 * 4);
  float* ar   = (float*)carve((size_t)N * 4 * 4);
  float* cvec = (float*)carve(128 * 4);
  int* offD = (int*)carve((size_t)(N + 1) * 4);
  int* offS = (int*)carve((size_t)(N + 1) * 4);
  int* lstD = (int*)carve((size_t)E * 4);
  int* lstS = (int*)carve((size_t)E * 4);
  char* zstart = cur;
  int* cntD = (int*)carve((size_t)N * 4);
  int* curD = (int*)carve((size_t)N * 4);
  int* cntS = (int*)carve((size_t)N * 4);
  int* curS = (int*)carve((size_t)N * 4);
  float* tacc = (float*)carve(64 * 4);
  size_t zbytes = (size_t)(cur - zstart);
  float* xres = (float*)d_out;

  hipMemsetAsync(zstart, 0, zbytes, stream);

  // CSR build
  k_count<<<(E + 255) / 256, 256, 0, stream>>>(src, dst, E, cntD, cntS);
  k_scan2<<<2, 1024, 0, stream>>>(cntD, offD, cntS, offS, N);
  k_fill<<<(E + 255) / 256, 256, 0, stream>>>(src, dst, E, offD, curD, lstD, offS, curS, lstS);

  // time path -> cvec
  k_time_reduce<<<256, 256, 0, stream>>>(et, tW1, tb1, tacc, E);
  k_time_combine<<<1, 128, 0, stream>>>(tacc, tW2, tb2, fW1, fb1, cvec, E);

  // conversions
  k_convX<<<(Mp * 64 + 255) / 256, 256, 0, stream>>>(x, xbf, N, Mp);
  k_padzero<<<Mp - N, 256, 0, stream>>>(habf, aggbf, N, Mp);
  {
    ConvArgs ca;
    int ts = 0;
    auto setd = [&](int i, const float* W, __hip_bfloat16* Wt, int K, int Nw) {
      ca.d[i] = ConvDesc{W, Wt, K, Nw, ts};
      ts += (K / 32) * (Nw / 64);
    };
    setd(0, W1, wt1, 64, 512);
    setd(1, W2, wt2, 512, 512);
    setd(2, W3, wt3, 512, 512);
    setd(3, rW, wtR, 64, 128);
    setd(4, fW1, wtF1, 128, 128);
    setd(5, fW2, wtF2, 128, 128);
    k_convAll<<<ts, 256, 0, stream>>>(ca);
  }

  const int TB = Mp / 128;  // 157
  const int GB = (N + 3) / 4;
  // x_res = x @ rW + rb -> d_out (f32)
  { dim3 g(TB, 1); gemm_bf16<<<g, 256, 0, stream>>>(xbf, wtR, xres, rb, N, 128, 64, 0, 0); }
  // layer 1
  { dim3 g(TB, 4); gemm_bf16<<<g, 256, 0, stream>>>(xbf, wt1, xlbf, nullptr, Mp, 512, 64, 0, 1); }
  k_alar<<<GB, 256, 0, stream>>>(xlbf, as1, ad1, al, ar, N);
  k_gat_agg<<<GB, 256, 0, stream>>>(xlbf, al, ar, offD, lstD, b1, habf, nullptr, 0, N);
  // layer 2
  { dim3 g(TB, 4); gemm_bf16<<<g, 256, 0, stream>>>(habf, wt2, xlbf, nullptr, Mp, 512, 512, 0, 1); }
  k_alar<<<GB, 256, 0, stream>>>(xlbf, as2, ad2, al, ar, N);
  k_gat_agg<<<GB, 256, 0, stream>>>(xlbf, al, ar, offD, lstD, b2, habf, nullptr, 0, N);
  // layer 3 (head-mean epilogue -> h3 bf16)
  { dim3 g(TB, 4); gemm_bf16<<<g, 256, 0, stream>>>(habf, wt3, xlbf, nullptr, Mp, 512, 512, 0, 1); }
  k_alar<<<GB, 256, 0, stream>>>(xlbf, as3, ad3, al, ar, N);
  k_gat_agg<<<GB, 256, 0, stream>>>(xlbf, al, ar, offD, lstD, b3, nullptr, h3, 1, N);

  // agg = segment_sum(h3[dst], src) -> bf16
  k_aggsrc<<<GB, 256, 0, stream>>>(h3, offS, lstS, aggbf, N);

  // z1 = relu(agg @ fW1[:128] + cvec) (bf16); z2 = z1 @ fW2 + fb2 (f32)
  {
    dim3 g(TB, 1);
    gemm_bf16<<<g, 256, 0, stream>>>(aggbf, wtF1, z1bf, cvec, Mp, 128, 128, 1, 1);
    gemm_bf16<<<g, 256, 0, stream>>>(z1bf, wtF2, z2, fb2, N, 128, 128, 0, 0);
  }

  // layernorm + residual -> d_out
  k_ln_res<<<N, 128, 0, stream>>>(z2, lng, lnb, xres);
}

// Round 6
// 406.959 us; speedup vs baseline: 2.6533x; 1.0971x over previous
//
#include <hip/hip_runtime.h>
#include <hip/hip_bf16.h>
#include <math.h>

typedef short bf16x8 __attribute__((ext_vector_type(8)));
typedef float f32x4 __attribute__((ext_vector_type(4)));

__device__ __forceinline__ float lrelu(float v) { return v > 0.f ? v : 0.2f * v; }

__device__ __forceinline__ void gload16(const void* g, void* l) {
  __builtin_amdgcn_global_load_lds(
      (const __attribute__((address_space(1))) void*)g,
      (__attribute__((address_space(3))) void*)l, 16, 0, 0);
}

__device__ __forceinline__ uint packbf(float v0, float v1) {
  __hip_bfloat16 h0 = __float2bfloat16(v0);
  __hip_bfloat16 h1 = __float2bfloat16(v1);
  return (uint)(*(unsigned short*)&h0) | ((uint)(*(unsigned short*)&h1) << 16);
}

// ---------------- degree count ----------------
__global__ void k_count(const int* __restrict__ src, const int* __restrict__ dst, int E,
                        int* cntD, int* cntS) {
  int e = blockIdx.x * blockDim.x + threadIdx.x;
  if (e < E) {
    atomicAdd(&cntD[dst[e]], 1);
    atomicAdd(&cntS[src[e]], 1);
  }
}

// ---------------- exclusive scans (block 0: D, block 1: S) ----------------
__global__ __launch_bounds__(1024) void k_scan2(const int* __restrict__ cntD, int* __restrict__ offD,
                                                const int* __restrict__ cntS, int* __restrict__ offS,
                                                int n) {
  const int* cnt = blockIdx.x ? cntS : cntD;
  int* off = blockIdx.x ? offS : offD;
  __shared__ int sums[1024];
  int t = threadIdx.x;
  int PT = (n + 1023) >> 10;
  int start = t * PT;
  int local = 0;
  for (int i = 0; i < PT; ++i) {
    int idx = start + i;
    if (idx < n) local += cnt[idx];
  }
  sums[t] = local;
  __syncthreads();
  for (int o = 1; o < 1024; o <<= 1) {
    int v = (t >= o) ? sums[t - o] : 0;
    __syncthreads();
    sums[t] += v;
    __syncthreads();
  }
  int run = sums[t] - local;
  for (int i = 0; i < PT; ++i) {
    int idx = start + i;
    if (idx < n) { off[idx] = run; run += cnt[idx]; }
  }
  if (t == 1023) off[n] = run;
}

// ---------------- fill CSR lists ----------------
__global__ void k_fill(const int* __restrict__ src, const int* __restrict__ dst, int E,
                       const int* __restrict__ offD, int* curD, int* lstD,
                       const int* __restrict__ offS, int* curS, int* lstS) {
  int e = blockIdx.x * blockDim.x + threadIdx.x;
  if (e < E) {
    int d = dst[e], s = src[e];
    int p = atomicAdd(&curD[d], 1);
    lstD[offD[d] + p] = s;
    int q = atomicAdd(&curS[s], 1);
    lstS[offS[s] + q] = d;
  }
}

// ---------------- time embedding: LDS tile + uniform broadcast reads ----------------
__global__ __launch_bounds__(256) void k_time_reduce(const float* __restrict__ et,
    const float* __restrict__ tW1, const float* __restrict__ tb1,
    float* __restrict__ tacc, int E) {
  __shared__ float se[256];
  __shared__ float buf[256];
  int t = threadIdx.x;
  int l = t & 63, w = t >> 6;
  float wk = tW1[l], bk = tb1[l];
  float a0 = 0.f, a1 = 0.f, a2 = 0.f, a3 = 0.f;
  for (int base = blockIdx.x * 256; base < E; base += gridDim.x * 256) {
    int idx = base + t;
    se[t] = (idx < E) ? et[idx] : 0.f;
    __syncthreads();
    int cnt = E - base; if (cnt > 256) cnt = 256;
    int s0 = w * 64;
    int c = cnt - s0; if (c < 0) c = 0; if (c > 64) c = 64;
    int j = 0;
    for (; j + 4 <= c; j += 4) {
      float v0 = se[s0 + j], v1 = se[s0 + j + 1];
      float v2 = se[s0 + j + 2], v3 = se[s0 + j + 3];
      a0 += fmaxf(v0 * wk + bk, 0.f);
      a1 += fmaxf(v1 * wk + bk, 0.f);
      a2 += fmaxf(v2 * wk + bk, 0.f);
      a3 += fmaxf(v3 * wk + bk, 0.f);
    }
    for (; j < c; ++j) a0 += fmaxf(se[s0 + j] * wk + bk, 0.f);
    __syncthreads();
  }
  buf[t] = (a0 + a1) + (a2 + a3);
  __syncthreads();
  if (t < 64) {
    float s = buf[t] + buf[t + 64] + buf[t + 128] + buf[t + 192];
    atomicAdd(&tacc[t], s);
  }
}

// ---------------- cvec = (mean @ tW2 + tb2) @ fW1[128:] + fb1 ----------------
__global__ __launch_bounds__(128) void k_time_combine(const float* __restrict__ tacc,
    const float* __restrict__ tW2, const float* __restrict__ tb2,
    const float* __restrict__ fW1, const float* __restrict__ fb1,
    float* __restrict__ cvec, int E) {
  __shared__ float tm[128];
  int t = threadIdx.x;
  float inv = 1.f / (float)E;
  float acc = tb2[t];
  for (int k = 0; k < 64; ++k) acc += (tacc[k] * inv) * tW2[k * 128 + t];
  tm[t] = acc;
  __syncthreads();
  float c = fb1[t];
  for (int k = 0; k < 128; ++k) c += tm[k] * fW1[(128 + k) * 128 + t];
  cvec[t] = c;
}

// ---------------- fused prep: weight transposes + x->bf16 + pad-zero ----------------
struct PrepArgs {
  const float* W[6]; __hip_bfloat16* Wt[6]; int K[6]; int Nw[6]; int tstart[6];
  int NC, XB;
};

__global__ __launch_bounds__(256) void k_prep(PrepArgs a, const float* __restrict__ x,
    __hip_bfloat16* __restrict__ xbf, __hip_bfloat16* __restrict__ habf,
    __hip_bfloat16* __restrict__ aggbf, int N, int Mp) {
  __shared__ float tile[32][65];
  int bid = blockIdx.x;
  int t = threadIdx.x;
  if (bid < a.NC) {
    int m = 0;
#pragma unroll
    for (int i = 1; i < 6; ++i) if (bid >= a.tstart[i]) m = i;
    const float* W = a.W[m];
    __hip_bfloat16* Wt = a.Wt[m];
    int K = a.K[m], Nw = a.Nw[m];
    int lt = bid - a.tstart[m];
    int ntn = Nw >> 6;
    int bk = (lt / ntn) * 32, bn = (lt % ntn) * 64;
    int rn = t & 63, rk = t >> 6;
#pragma unroll
    for (int i = 0; i < 8; ++i)
      tile[rk + i * 4][rn] = W[(size_t)(bk + rk + i * 4) * Nw + bn + rn];
    __syncthreads();
    int wk2 = (t & 15) * 2, wn = t >> 4;
    uint* Wo = (uint*)Wt;
#pragma unroll
    for (int i = 0; i < 4; ++i) {
      int n = wn + i * 16;
      Wo[((size_t)(bn + n) * K + bk + wk2) >> 1] = packbf(tile[wk2][n], tile[wk2 + 1][n]);
    }
  } else if (bid < a.NC + a.XB) {
    int i4 = (bid - a.NC) * 256 + t;
    int row = i4 >> 4;
    float4 v = make_float4(0.f, 0.f, 0.f, 0.f);
    if (row < N) v = ((const float4*)x)[i4];
    uint2 p; p.x = packbf(v.x, v.y); p.y = packbf(v.z, v.w);
    ((uint2*)xbf)[i4] = p;
  } else {
    int row = N + (bid - a.NC - a.XB);
    ((uint*)habf)[(size_t)row * 256 + t] = 0;
    if (t < 64) ((uint*)aggbf)[(size_t)row * 64 + t] = 0;
  }
}

// ---------------- bf16 MFMA GEMM with fused epilogues ----------------
// EPI 0: bf16 out (stride Nw), bias(optional)+relu(optional)
// EPI 1: col-blocks 0..3 -> bf16 out stride 512 (no bias/relu) + alar dots;
//        col-block 4 -> f32 C2 stride 128 with bias2
// EPI 2: f32 z=acc+bias, per-row LayerNorm(lng,lnb), += resid, write resid (f32)
template<int EPI>
__global__ __launch_bounds__(256) void gemm_t(
    const __hip_bfloat16* __restrict__ A, const __hip_bfloat16* __restrict__ Bt,
    void* __restrict__ Cout, const float* __restrict__ bias,
    int M, int Nw, int K, int relu, int Nn,
    const float* __restrict__ asrc, const float* __restrict__ adst,
    float* __restrict__ al, float* __restrict__ ar,
    float* __restrict__ C2, const float* __restrict__ bias2,
    const float* __restrict__ lng, const float* __restrict__ lnb,
    float* __restrict__ resid)
{
  __shared__ short As[128 * 32];
  __shared__ short Bs[128 * 32];
  int tid = threadIdx.x;
  int bm = blockIdx.x * 128;
  int cb = blockIdx.y;
  int bn = cb * 128;
  int w = tid >> 6, l = tid & 63;
  int wr = (w >> 1) * 64, wc = (w & 1) * 64;
  f32x4 acc[4][4] = {};
  const short* Ag = (const short*)A;
  const short* Bg = (const short*)Bt;

  for (int k0 = 0; k0 < K; k0 += 32) {
#pragma unroll
    for (int i = 0; i < 2; ++i) {
      int slot = i * 256 + tid;
      int row = slot >> 2;
      int col = (slot & 3) * 8;
      gload16(Ag + (size_t)(bm + row) * K + k0 + col, &As[slot * 8]);
      gload16(Bg + (size_t)(bn + row) * K + k0 + col, &Bs[slot * 8]);
    }
    __syncthreads();
    bf16x8 af[4], bfr[4];
#pragma unroll
    for (int m = 0; m < 4; ++m)
      af[m] = *(const bf16x8*)&As[(wr + m * 16 + (l & 15)) * 32 + (l >> 4) * 8];
#pragma unroll
    for (int n = 0; n < 4; ++n)
      bfr[n] = *(const bf16x8*)&Bs[(wc + n * 16 + (l & 15)) * 32 + (l >> 4) * 8];
#pragma unroll
    for (int m = 0; m < 4; ++m)
#pragma unroll
      for (int n = 0; n < 4; ++n)
        acc[m][n] = __builtin_amdgcn_mfma_f32_16x16x32_bf16(af[m], bfr[n], acc[m][n], 0, 0, 0);
    __syncthreads();
  }

  int g = l >> 4, cc = l & 15, cr = g * 4;

  if (EPI == 0) {
#pragma unroll
    for (int n = 0; n < 4; ++n) {
      int col = bn + wc + n * 16 + cc;
      float bb = bias ? bias[col] : 0.f;
#pragma unroll
      for (int m = 0; m < 4; ++m) {
#pragma unroll
        for (int r = 0; r < 4; ++r) {
          int gm = bm + wr + m * 16 + cr + r;
          if (gm < M) {
            float v = acc[m][n][r] + bb;
            if (relu) v = fmaxf(v, 0.f);
            ((__hip_bfloat16*)Cout)[(size_t)gm * Nw + col] = __float2bfloat16(v);
          }
        }
      }
    }
  }

  if (EPI == 1) {
    if (cb < 4) {
#pragma unroll
      for (int n = 0; n < 4; ++n) {
        int col = bn + wc + n * 16 + cc;
#pragma unroll
        for (int m = 0; m < 4; ++m) {
#pragma unroll
          for (int r = 0; r < 4; ++r) {
            int gm = bm + wr + m * 16 + cr + r;
            if (gm < M)
              ((__hip_bfloat16*)Cout)[(size_t)gm * 512 + col] = __float2bfloat16(acc[m][n][r]);
          }
        }
      }
      // fused al/ar dots for head h = cb (its 128 channels == this col-block)
      float asv[4], adv[4];
#pragma unroll
      for (int n = 0; n < 4; ++n) {
        int ch = bn + wc + n * 16 + cc;
        asv[n] = asrc[ch]; adv[n] = adst[ch];
      }
      float* spal = (float*)As;
      float* spar = spal + 256;
#pragma unroll
      for (int m = 0; m < 4; ++m) {
#pragma unroll
        for (int r = 0; r < 4; ++r) {
          float pa = acc[m][0][r] * asv[0] + acc[m][1][r] * asv[1]
                   + acc[m][2][r] * asv[2] + acc[m][3][r] * asv[3];
          float pb = acc[m][0][r] * adv[0] + acc[m][1][r] * adv[1]
                   + acc[m][2][r] * adv[2] + acc[m][3][r] * adv[3];
#pragma unroll
          for (int o = 1; o < 16; o <<= 1) {
            pa += __shfl_xor(pa, o);
            pb += __shfl_xor(pb, o);
          }
          if (cc == 0) {
            int rl = m * 16 + cr + r;
            spal[w * 64 + rl] = pa;
            spar[w * 64 + rl] = pb;
          }
        }
      }
      __syncthreads();
      if ((w & 1) == 0) {
        float av = spal[w * 64 + l] + spal[(w + 1) * 64 + l];
        float rv = spar[w * 64 + l] + spar[(w + 1) * 64 + l];
        int row = bm + wr + l;
        if (row < Nn) { al[row * 4 + cb] = av; ar[row * 4 + cb] = rv; }
      }
    } else {
#pragma unroll
      for (int n = 0; n < 4; ++n) {
        int col2 = wc + n * 16 + cc;
        float bb = bias2[col2];
#pragma unroll
        for (int m = 0; m < 4; ++m) {
#pragma unroll
          for (int r = 0; r < 4; ++r) {
            int gm = bm + wr + m * 16 + cr + r;
            if (gm < Nn) C2[(size_t)gm * 128 + col2] = acc[m][n][r] + bb;
          }
        }
      }
    }
  }

  if (EPI == 2) {
    float bb[4], gl_[4], gb_[4];
#pragma unroll
    for (int n = 0; n < 4; ++n) {
      int col = wc + n * 16 + cc;
      bb[n] = bias[col]; gl_[n] = lng[col]; gb_[n] = lnb[col];
    }
    float* ssum = (float*)As;
    float* ssq = ssum + 256;
    float* smu = ssum + 512;
    float* srs = ssum + 640;
#pragma unroll
    for (int m = 0; m < 4; ++m) {
#pragma unroll
      for (int r = 0; r < 4; ++r) {
        float s = 0.f, q = 0.f;
#pragma unroll
        for (int n = 0; n < 4; ++n) {
          float z = acc[m][n][r] + bb[n];
          s += z; q += z * z;
        }
#pragma unroll
        for (int o = 1; o < 16; o <<= 1) {
          s += __shfl_xor(s, o);
          q += __shfl_xor(q, o);
        }
        if (cc == 0) {
          int rl = m * 16 + cr + r;
          ssum[w * 64 + rl] = s;
          ssq[w * 64 + rl] = q;
        }
      }
    }
    __syncthreads();
    if ((w & 1) == 0) {
      float s = ssum[w * 64 + l] + ssum[(w + 1) * 64 + l];
      float q = ssq[w * 64 + l] + ssq[(w + 1) * 64 + l];
      float mu = s * (1.f / 128.f);
      float var = q * (1.f / 128.f) - mu * mu;
      smu[wr + l] = mu;
      srs[wr + l] = rsqrtf(var + 1e-5f);
    }
    __syncthreads();
#pragma unroll
    for (int m = 0; m < 4; ++m) {
#pragma unroll
      for (int r = 0; r < 4; ++r) {
        int rl = wr + m * 16 + cr + r;
        int gm = bm + rl;
        if (gm < M) {
          float mu = smu[rl], rs = srs[rl];
#pragma unroll
          for (int n = 0; n < 4; ++n) {
            int col = wc + n * 16 + cc;
            float z = acc[m][n][r] + bb[n];
            float y = (z - mu) * rs * gl_[n] + gb_[n] + resid[(size_t)gm * 128 + col];
            resid[(size_t)gm * 128 + col] = y;
          }
        }
      }
    }
  }
}

// ---------------- GAT aggregation: wave per dst node, no max pass ----------------
__global__ __launch_bounds__(256) void k_gat_agg(
    const __hip_bfloat16* __restrict__ xl, const float* __restrict__ al,
    const float* __restrict__ ar, const int* __restrict__ off,
    const int* __restrict__ lst, const float* __restrict__ bias,
    __hip_bfloat16* __restrict__ outb, __hip_bfloat16* __restrict__ outh,
    int mode, int N)
{
  __shared__ int   sside[4][64];
  __shared__ float sebuf[4][4][68];
  int w = threadIdx.x >> 6, l = threadIdx.x & 63;
  int d = blockIdx.x * 4 + w;
  bool active = (d < N);
  int base = 0, deg = 0, tot = 0;
  float4 arv = make_float4(0.f, 0.f, 0.f, 0.f);
  if (active) {
    base = off[d]; deg = off[d + 1] - base; tot = deg + 1;
    arv = *(const float4*)(ar + 4 * d);
  }
  int hh = l >> 4;
  float facc[8] = {0.f, 0.f, 0.f, 0.f, 0.f, 0.f, 0.f, 0.f};
  float dn0 = 0.f, dn1 = 0.f, dn2 = 0.f, dn3 = 0.f;
  const uint4* xw = (const uint4*)xl;
  for (int cb = 0; cb < tot; cb += 64) {
    int j = cb + l;
    float e0 = 0.f, e1 = 0.f, e2 = 0.f, e3 = 0.f;
    int sid = 0;
    if (j < tot) {
      sid = (j == deg) ? d : lst[base + j];
      float4 av = *(const float4*)(al + 4 * sid);
      e0 = __expf(lrelu(av.x + arv.x));
      e1 = __expf(lrelu(av.y + arv.y));
      e2 = __expf(lrelu(av.z + arv.z));
      e3 = __expf(lrelu(av.w + arv.w));
      dn0 += e0; dn1 += e1; dn2 += e2; dn3 += e3;
    }
    sside[w][l] = sid;
    sebuf[w][0][l] = e0; sebuf[w][1][l] = e1;
    sebuf[w][2][l] = e2; sebuf[w][3][l] = e3;
    int cnt = tot - cb; if (cnt > 64) cnt = 64;
#pragma unroll 2
    for (int jj = 0; jj < cnt; ++jj) {
      int sid2 = sside[w][jj];
      float e = sebuf[w][hh][jj];
      uint4 pv = xw[(size_t)sid2 * 64 + l];
      facc[0] += e * __uint_as_float(pv.x << 16);
      facc[1] += e * __uint_as_float(pv.x & 0xffff0000u);
      facc[2] += e * __uint_as_float(pv.y << 16);
      facc[3] += e * __uint_as_float(pv.y & 0xffff0000u);
      facc[4] += e * __uint_as_float(pv.z << 16);
      facc[5] += e * __uint_as_float(pv.z & 0xffff0000u);
      facc[6] += e * __uint_as_float(pv.w << 16);
      facc[7] += e * __uint_as_float(pv.w & 0xffff0000u);
    }
  }
#pragma unroll
  for (int o = 1; o < 64; o <<= 1) {
    dn0 += __shfl_xor(dn0, o); dn1 += __shfl_xor(dn1, o);
    dn2 += __shfl_xor(dn2, o); dn3 += __shfl_xor(dn3, o);
  }
  if (!active) return;
  float dsel = hh == 0 ? dn0 : hh == 1 ? dn1 : hh == 2 ? dn2 : dn3;
  float rden = 1.f / dsel;
  if (mode == 0) {
    int c8 = l * 8;
    const float4* bp = (const float4*)(bias + c8);
    float4 b0 = bp[0], b1 = bp[1];
    float vb[8] = {b0.x, b0.y, b0.z, b0.w, b1.x, b1.y, b1.z, b1.w};
    uint4 o4; uint* po = (uint*)&o4;
#pragma unroll
    for (int i = 0; i < 4; ++i) {
      float v0 = fmaxf(facc[2*i]   * rden + vb[2*i],   0.f);
      float v1 = fmaxf(facc[2*i+1] * rden + vb[2*i+1], 0.f);
      po[i] = packbf(v0, v1);
    }
    ((uint4*)outb)[(size_t)d * 64 + l] = o4;
  } else {
#pragma unroll
    for (int i = 0; i < 8; ++i) {
      facc[i] *= rden;
      facc[i] += __shfl_xor(facc[i], 16);
      facc[i] += __shfl_xor(facc[i], 32);
    }
    if (l < 16) {
      int c = l * 8;
      const float4* bp = (const float4*)(bias + c);
      float4 b0 = bp[0], b1 = bp[1];
      float vb[8] = {b0.x, b0.y, b0.z, b0.w, b1.x, b1.y, b1.z, b1.w};
      uint4 o4; uint* po = (uint*)&o4;
#pragma unroll
      for (int i = 0; i < 4; ++i) {
        float v0 = fmaxf(facc[2*i]   * 0.25f + vb[2*i],   0.f);
        float v1 = fmaxf(facc[2*i+1] * 0.25f + vb[2*i+1], 0.f);
        po[i] = packbf(v0, v1);
      }
      ((uint4*)outh)[(size_t)d * 16 + l] = o4;
    }
  }
}

// ---------------- final src-side segment sum (h3 bf16 -> aggbf bf16) ----------------
__global__ __launch_bounds__(256) void k_aggsrc(const __hip_bfloat16* __restrict__ h3,
    const int* __restrict__ off, const int* __restrict__ lst,
    __hip_bfloat16* __restrict__ out, int N) {
  int w = threadIdx.x >> 6, l = threadIdx.x & 63;
  int n = blockIdx.x * 4 + w;
  if (n >= N) return;
  const uint* hw = (const uint*)h3;
  uint pv = hw[(size_t)n * 64 + l];
  float a0 = __uint_as_float(pv << 16);
  float a1 = __uint_as_float(pv & 0xffff0000u);
  float b0 = 0.f, b1 = 0.f;
  int b = off[n], e = off[n + 1];
  int j = b;
  for (; j + 2 <= e; j += 2) {
    int s0 = lst[j], s1 = lst[j + 1];
    uint q0 = hw[(size_t)s0 * 64 + l];
    uint q1 = hw[(size_t)s1 * 64 + l];
    a0 += __uint_as_float(q0 << 16);
    a1 += __uint_as_float(q0 & 0xffff0000u);
    b0 += __uint_as_float(q1 << 16);
    b1 += __uint_as_float(q1 & 0xffff0000u);
  }
  if (j < e) {
    uint q = hw[(size_t)lst[j] * 64 + l];
    a0 += __uint_as_float(q << 16);
    a1 += __uint_as_float(q & 0xffff0000u);
  }
  ((uint*)out)[(size_t)n * 64 + l] = packbf(a0 + b0, a1 + b1);
}

extern "C" void kernel_launch(void* const* d_in, const int* in_sizes, int n_in,
                              void* d_out, int out_size, void* d_ws, size_t ws_size,
                              hipStream_t stream) {
  (void)n_in; (void)out_size; (void)ws_size;
  const float* x   = (const float*)d_in[0];
  const float* et  = (const float*)d_in[1];
  const float* W1  = (const float*)d_in[2];
  const float* as1 = (const float*)d_in[3];
  const float* ad1 = (const float*)d_in[4];
  const float* b1  = (const float*)d_in[5];
  const float* W2  = (const float*)d_in[6];
  const float* as2 = (const float*)d_in[7];
  const float* ad2 = (const float*)d_in[8];
  const float* b2  = (const float*)d_in[9];
  const float* W3  = (const float*)d_in[10];
  const float* as3 = (const float*)d_in[11];
  const float* ad3 = (const float*)d_in[12];
  const float* b3  = (const float*)d_in[13];
  const float* tW1 = (const float*)d_in[14];
  const float* tb1 = (const float*)d_in[15];
  const float* tW2 = (const float*)d_in[16];
  const float* tb2 = (const float*)d_in[17];
  const float* fW1 = (const float*)d_in[18];
  const float* fb1 = (const float*)d_in[19];
  const float* fW2 = (const float*)d_in[20];
  const float* fb2 = (const float*)d_in[21];
  const float* lng = (const float*)d_in[22];
  const float* lnb = (const float*)d_in[23];
  const float* rW  = (const float*)d_in[24];
  const float* rb  = (const float*)d_in[25];
  const int*   ei  = (const int*)d_in[26];
  const int N = in_sizes[0] / 64;     // 20000
  const int E = in_sizes[26] / 2;     // 320000
  const int Mp = ((N + 127) / 128) * 128;  // 20096
  const int* src = ei;
  const int* dst = ei + E;

  char* cur = (char*)d_ws;
  auto carve = [&](size_t bytes) { char* p = cur; cur += (bytes + 255) & ~(size_t)255; return p; };
  __hip_bfloat16* xbf  = (__hip_bfloat16*)carve((size_t)Mp * 64 * 2);
  __hip_bfloat16* habf = (__hip_bfloat16*)carve((size_t)Mp * 512 * 2);
  __hip_bfloat16* xlbf = (__hip_bfloat16*)carve((size_t)Mp * 512 * 2);
  __hip_bfloat16* wtCat= (__hip_bfloat16*)carve((size_t)640 * 64 * 2);  // [W1t(512); rWt(128)]
  __hip_bfloat16* wt2  = (__hip_bfloat16*)carve((size_t)512 * 512 * 2);
  __hip_bfloat16* wt3  = (__hip_bfloat16*)carve((size_t)512 * 512 * 2);
  __hip_bfloat16* wtF1 = (__hip_bfloat16*)carve((size_t)128 * 128 * 2);
  __hip_bfloat16* wtF2 = (__hip_bfloat16*)carve((size_t)128 * 128 * 2);
  __hip_bfloat16* aggbf= (__hip_bfloat16*)carve((size_t)Mp * 128 * 2);
  __hip_bfloat16* z1bf = (__hip_bfloat16*)carve((size_t)Mp * 128 * 2);
  __hip_bfloat16* h3   = (__hip_bfloat16*)carve((size_t)N * 128 * 2);
  float* al   = (float*)carve((size_t)N * 4 * 4);
  float* ar   = (float*)carve((size_t)N * 4 * 4);
  float* cvec = (float*)carve(128 * 4);
  int* offD = (int*)carve((size_t)(N + 1) * 4);
  int* offS = (int*)carve((size_t)(N + 1) * 4);
  int* lstD = (int*)carve((size_t)E * 4);
  int* lstS = (int*)carve((size_t)E * 4);
  char* zstart = cur;
  int* cntD = (int*)carve((size_t)N * 4);
  int* curD = (int*)carve((size_t)N * 4);
  int* cntS = (int*)carve((size_t)N * 4);
  int* curS = (int*)carve((size_t)N * 4);
  float* tacc = (float*)carve(64 * 4);
  size_t zbytes = (size_t)(cur - zstart);
  float* xres = (float*)d_out;

  hipMemsetAsync(zstart, 0, zbytes, stream);

  // CSR build
  k_count<<<(E + 255) / 256, 256, 0, stream>>>(src, dst, E, cntD, cntS);
  k_scan2<<<2, 1024, 0, stream>>>(cntD, offD, cntS, offS, N);
  k_fill<<<(E + 255) / 256, 256, 0, stream>>>(src, dst, E, offD, curD, lstD, offS, curS, lstS);

  // time path -> cvec
  k_time_reduce<<<256, 256, 0, stream>>>(et, tW1, tb1, tacc, E);
  k_time_combine<<<1, 128, 0, stream>>>(tacc, tW2, tb2, fW1, fb1, cvec, E);

  // fused prep: weight transposes + x conversion + pad zero
  {
    PrepArgs pa;
    int ts = 0;
    auto setd = [&](int i, const float* W, __hip_bfloat16* Wt, int K, int Nw) {
      pa.W[i] = W; pa.Wt[i] = Wt; pa.K[i] = K; pa.Nw[i] = Nw; pa.tstart[i] = ts;
      ts += (K / 32) * (Nw / 64);
    };
    setd(0, W1, wtCat, 64, 512);
    setd(1, W2, wt2, 512, 512);
    setd(2, W3, wt3, 512, 512);
    setd(3, rW, wtCat + (size_t)512 * 64, 64, 128);
    setd(4, fW1, wtF1, 128, 128);
    setd(5, fW2, wtF2, 128, 128);
    pa.NC = ts;
    pa.XB = Mp / 16;
    int grid = pa.NC + pa.XB + (Mp - N);
    k_prep<<<grid, 256, 0, stream>>>(pa, x, xbf, habf, aggbf, N, Mp);
  }

  const int TB = Mp / 128;  // 157
  const int GB = (N + 3) / 4;

  // layer 1 fused with x_res: xl1 = x@W1 (bf16, +alar), xres = x@rW + rb (f32, col-block 4)
  gemm_t<1><<<dim3(TB, 5), 256, 0, stream>>>(xbf, wtCat, xlbf, nullptr, Mp, 640, 64, 0, N,
      as1, ad1, al, ar, xres, rb, nullptr, nullptr, nullptr);
  k_gat_agg<<<GB, 256, 0, stream>>>(xlbf, al, ar, offD, lstD, b1, habf, nullptr, 0, N);
  // layer 2
  gemm_t<1><<<dim3(TB, 4), 256, 0, stream>>>(habf, wt2, xlbf, nullptr, Mp, 512, 512, 0, N,
      as2, ad2, al, ar, nullptr, nullptr, nullptr, nullptr, nullptr);
  k_gat_agg<<<GB, 256, 0, stream>>>(xlbf, al, ar, offD, lstD, b2, habf, nullptr, 0, N);
  // layer 3 (head-mean epilogue -> h3 bf16)
  gemm_t<1><<<dim3(TB, 4), 256, 0, stream>>>(habf, wt3, xlbf, nullptr, Mp, 512, 512, 0, N,
      as3, ad3, al, ar, nullptr, nullptr, nullptr, nullptr, nullptr);
  k_gat_agg<<<GB, 256, 0, stream>>>(xlbf, al, ar, offD, lstD, b3, nullptr, h3, 1, N);

  // agg = segment_sum(h3[dst], src) -> bf16
  k_aggsrc<<<GB, 256, 0, stream>>>(h3, offS, lstS, aggbf, N);

  // z1 = relu(agg @ fW1[:128] + cvec) (bf16)
  gemm_t<0><<<dim3(TB, 1), 256, 0, stream>>>(aggbf, wtF1, z1bf, cvec, Mp, 128, 128, 1, N,
      nullptr, nullptr, nullptr, nullptr, nullptr, nullptr, nullptr, nullptr, nullptr);
  // z2 = z1 @ fW2 + fb2, fused LN + residual -> d_out
  gemm_t<2><<<dim3(TB, 1), 256, 0, stream>>>(z1bf, wtF2, nullptr, fb2, N, 128, 128, 0, N,
      nullptr, nullptr, nullptr, nullptr, nullptr, nullptr, lng, lnb, xres);
}

// Round 7
// 380.447 us; speedup vs baseline: 2.8382x; 1.0697x over previous
//
#include <hip/hip_runtime.h>
#include <hip/hip_bf16.h>
#include <math.h>

typedef short bf16x8 __attribute__((ext_vector_type(8)));
typedef float f32x4 __attribute__((ext_vector_type(4)));

__device__ __forceinline__ float lrelu(float v) { return v > 0.f ? v : 0.2f * v; }

__device__ __forceinline__ void gload16(const void* g, void* l) {
  __builtin_amdgcn_global_load_lds(
      (const __attribute__((address_space(1))) void*)g,
      (__attribute__((address_space(3))) void*)l, 16, 0, 0);
}

__device__ __forceinline__ uint packbf(float v0, float v1) {
  __hip_bfloat16 h0 = __float2bfloat16(v0);
  __hip_bfloat16 h1 = __float2bfloat16(v1);
  return (uint)(*(unsigned short*)&h0) | ((uint)(*(unsigned short*)&h1) << 16);
}

// ---------------- degree count + (first 256 blocks) time-embed partial sums ----------------
__global__ __launch_bounds__(256) void k_countT(const int* __restrict__ src,
    const int* __restrict__ dst, int E, int* cntD, int* cntS,
    const float* __restrict__ et, const float* __restrict__ tW1,
    const float* __restrict__ tb1, float* __restrict__ tacc) {
  int t = threadIdx.x;
  int e = blockIdx.x * 256 + t;
  if (e < E) {
    atomicAdd(&cntD[dst[e]], 1);
    atomicAdd(&cntS[src[e]], 1);
  }
  if (blockIdx.x < 256) {
    __shared__ float se[256];
    __shared__ float buf[256];
    int l = t & 63, w = t >> 6;
    float wk = tW1[l], bk = tb1[l];
    float a0 = 0.f, a1 = 0.f, a2 = 0.f, a3 = 0.f;
    for (int base = blockIdx.x * 256; base < E; base += 256 * 256) {
      int idx = base + t;
      se[t] = (idx < E) ? et[idx] : 0.f;
      __syncthreads();
      int cnt = E - base; if (cnt > 256) cnt = 256;
      int s0 = w * 64;
      int c = cnt - s0; if (c < 0) c = 0; if (c > 64) c = 64;
      int j = 0;
      for (; j + 4 <= c; j += 4) {
        a0 += fmaxf(se[s0 + j] * wk + bk, 0.f);
        a1 += fmaxf(se[s0 + j + 1] * wk + bk, 0.f);
        a2 += fmaxf(se[s0 + j + 2] * wk + bk, 0.f);
        a3 += fmaxf(se[s0 + j + 3] * wk + bk, 0.f);
      }
      for (; j < c; ++j) a0 += fmaxf(se[s0 + j] * wk + bk, 0.f);
      __syncthreads();
    }
    buf[t] = (a0 + a1) + (a2 + a3);
    __syncthreads();
    if (t < 64) {
      float s = buf[t] + buf[t + 64] + buf[t + 128] + buf[t + 192];
      atomicAdd(&tacc[t], s);
    }
  }
}

// ---------------- scans (blocks 0,1) + time-combine (block 2) ----------------
__global__ __launch_bounds__(1024) void k_scan2c(const int* __restrict__ cntD, int* __restrict__ offD,
    const int* __restrict__ cntS, int* __restrict__ offS, int n,
    const float* __restrict__ tacc, const float* __restrict__ tW2,
    const float* __restrict__ tb2, const float* __restrict__ fW1,
    const float* __restrict__ fb1, float* __restrict__ cvec, int E) {
  int t = threadIdx.x;
  if (blockIdx.x == 2) {
    __shared__ float tm[128];
    if (t < 128) {
      float inv = 1.f / (float)E;
      float acc = tb2[t];
      for (int k = 0; k < 64; ++k) acc += (tacc[k] * inv) * tW2[k * 128 + t];
      tm[t] = acc;
    }
    __syncthreads();
    if (t < 128) {
      float c = fb1[t];
      for (int k = 0; k < 128; ++k) c += tm[k] * fW1[(128 + k) * 128 + t];
      cvec[t] = c;
    }
    return;
  }
  const int* cnt = blockIdx.x ? cntS : cntD;
  int* off = blockIdx.x ? offS : offD;
  __shared__ int sums[1024];
  int PT = (n + 1023) >> 10;
  int start = t * PT;
  int local = 0;
  for (int i = 0; i < PT; ++i) {
    int idx = start + i;
    if (idx < n) local += cnt[idx];
  }
  sums[t] = local;
  __syncthreads();
  for (int o = 1; o < 1024; o <<= 1) {
    int v = (t >= o) ? sums[t - o] : 0;
    __syncthreads();
    sums[t] += v;
    __syncthreads();
  }
  int run = sums[t] - local;
  for (int i = 0; i < PT; ++i) {
    int idx = start + i;
    if (idx < n) { off[idx] = run; run += cnt[idx]; }
  }
  if (t == 1023) off[n] = run;
}

// ---------------- fill CSR lists ----------------
__global__ void k_fill(const int* __restrict__ src, const int* __restrict__ dst, int E,
                       const int* __restrict__ offD, int* curD, int* lstD,
                       const int* __restrict__ offS, int* curS, int* lstS) {
  int e = blockIdx.x * blockDim.x + threadIdx.x;
  if (e < E) {
    int d = dst[e], s = src[e];
    int p = atomicAdd(&curD[d], 1);
    lstD[offD[d] + p] = s;
    int q = atomicAdd(&curS[s], 1);
    lstS[offS[s] + q] = d;
  }
}

// ---------------- fused prep: weight transposes + x->bf16 + pad-zero ----------------
struct PrepArgs {
  const float* W[6]; __hip_bfloat16* Wt[6]; int K[6]; int Nw[6]; int tstart[6];
  int NC, XB;
};

__global__ __launch_bounds__(256) void k_prep(PrepArgs a, const float* __restrict__ x,
    __hip_bfloat16* __restrict__ xbf, __hip_bfloat16* __restrict__ habf,
    __hip_bfloat16* __restrict__ aggbf, int N, int Mp) {
  __shared__ float tile[32][65];
  int bid = blockIdx.x;
  int t = threadIdx.x;
  if (bid < a.NC) {
    int m = 0;
#pragma unroll
    for (int i = 1; i < 6; ++i) if (bid >= a.tstart[i]) m = i;
    const float* W = a.W[m];
    __hip_bfloat16* Wt = a.Wt[m];
    int K = a.K[m], Nw = a.Nw[m];
    int lt = bid - a.tstart[m];
    int ntn = Nw >> 6;
    int bk = (lt / ntn) * 32, bn = (lt % ntn) * 64;
    int rn = t & 63, rk = t >> 6;
#pragma unroll
    for (int i = 0; i < 8; ++i)
      tile[rk + i * 4][rn] = W[(size_t)(bk + rk + i * 4) * Nw + bn + rn];
    __syncthreads();
    int wk2 = (t & 15) * 2, wn = t >> 4;
    uint* Wo = (uint*)Wt;
#pragma unroll
    for (int i = 0; i < 4; ++i) {
      int n = wn + i * 16;
      Wo[((size_t)(bn + n) * K + bk + wk2) >> 1] = packbf(tile[wk2][n], tile[wk2 + 1][n]);
    }
  } else if (bid < a.NC + a.XB) {
    int i4 = (bid - a.NC) * 256 + t;
    int row = i4 >> 4;
    float4 v = make_float4(0.f, 0.f, 0.f, 0.f);
    if (row < N) v = ((const float4*)x)[i4];
    uint2 p; p.x = packbf(v.x, v.y); p.y = packbf(v.z, v.w);
    ((uint2*)xbf)[i4] = p;
  } else {
    int row = N + (bid - a.NC - a.XB);
    ((uint*)habf)[(size_t)row * 256 + t] = 0;
    if (t < 64) ((uint*)aggbf)[(size_t)row * 64 + t] = 0;
  }
}

// ---------------- bf16 MFMA GEMM, BK=64 (two 32-col sub-tiles), fused epilogues ----------------
// EPI 0: bf16 out (stride Nw), bias(optional)+relu(optional)
// EPI 1: col-blocks 0..3 -> bf16 out stride 512 + alar dots; col-block 4 -> f32 C2 + bias2
// EPI 2: f32 z=acc+bias, per-row LayerNorm, += resid (f32, in place)
template<int EPI>
__global__ __launch_bounds__(256) void gemm_t(
    const __hip_bfloat16* __restrict__ A, const __hip_bfloat16* __restrict__ Bt,
    void* __restrict__ Cout, const float* __restrict__ bias,
    int M, int Nw, int K, int relu, int Nn,
    const float* __restrict__ asrc, const float* __restrict__ adst,
    float* __restrict__ al, float* __restrict__ ar,
    float* __restrict__ C2, const float* __restrict__ bias2,
    const float* __restrict__ lng, const float* __restrict__ lnb,
    float* __restrict__ resid)
{
  __shared__ short As0[128 * 32];
  __shared__ short As1[128 * 32];
  __shared__ short Bs0[128 * 32];
  __shared__ short Bs1[128 * 32];
  int tid = threadIdx.x;
  int bm = blockIdx.x * 128;
  int cb = blockIdx.y;
  int bn = cb * 128;
  int w = tid >> 6, l = tid & 63;
  int wr = (w >> 1) * 64, wc = (w & 1) * 64;
  f32x4 acc[4][4] = {};
  const short* Ag = (const short*)A;
  const short* Bg = (const short*)Bt;

  for (int k0 = 0; k0 < K; k0 += 64) {
#pragma unroll
    for (int i = 0; i < 2; ++i) {
      int slot = i * 256 + tid;
      int row = slot >> 2;
      int col = (slot & 3) * 8;
      const short* Arow = Ag + (size_t)(bm + row) * K + k0 + col;
      const short* Brow = Bg + (size_t)(bn + row) * K + k0 + col;
      gload16(Arow, &As0[slot * 8]);
      gload16(Arow + 32, &As1[slot * 8]);
      gload16(Brow, &Bs0[slot * 8]);
      gload16(Brow + 32, &Bs1[slot * 8]);
    }
    __syncthreads();
    {
      bf16x8 af[4], bfr[4];
#pragma unroll
      for (int m = 0; m < 4; ++m)
        af[m] = *(const bf16x8*)&As0[(wr + m * 16 + (l & 15)) * 32 + (l >> 4) * 8];
#pragma unroll
      for (int n = 0; n < 4; ++n)
        bfr[n] = *(const bf16x8*)&Bs0[(wc + n * 16 + (l & 15)) * 32 + (l >> 4) * 8];
#pragma unroll
      for (int m = 0; m < 4; ++m)
#pragma unroll
        for (int n = 0; n < 4; ++n)
          acc[m][n] = __builtin_amdgcn_mfma_f32_16x16x32_bf16(af[m], bfr[n], acc[m][n], 0, 0, 0);
    }
    {
      bf16x8 af[4], bfr[4];
#pragma unroll
      for (int m = 0; m < 4; ++m)
        af[m] = *(const bf16x8*)&As1[(wr + m * 16 + (l & 15)) * 32 + (l >> 4) * 8];
#pragma unroll
      for (int n = 0; n < 4; ++n)
        bfr[n] = *(const bf16x8*)&Bs1[(wc + n * 16 + (l & 15)) * 32 + (l >> 4) * 8];
#pragma unroll
      for (int m = 0; m < 4; ++m)
#pragma unroll
        for (int n = 0; n < 4; ++n)
          acc[m][n] = __builtin_amdgcn_mfma_f32_16x16x32_bf16(af[m], bfr[n], acc[m][n], 0, 0, 0);
    }
    __syncthreads();
  }

  int g = l >> 4, cc = l & 15, cr = g * 4;

  if (EPI == 0) {
#pragma unroll
    for (int n = 0; n < 4; ++n) {
      int col = bn + wc + n * 16 + cc;
      float bb = bias ? bias[col] : 0.f;
#pragma unroll
      for (int m = 0; m < 4; ++m) {
#pragma unroll
        for (int r = 0; r < 4; ++r) {
          int gm = bm + wr + m * 16 + cr + r;
          if (gm < M) {
            float v = acc[m][n][r] + bb;
            if (relu) v = fmaxf(v, 0.f);
            ((__hip_bfloat16*)Cout)[(size_t)gm * Nw + col] = __float2bfloat16(v);
          }
        }
      }
    }
  }

  if (EPI == 1) {
    if (cb < 4) {
#pragma unroll
      for (int n = 0; n < 4; ++n) {
        int col = bn + wc + n * 16 + cc;
#pragma unroll
        for (int m = 0; m < 4; ++m) {
#pragma unroll
          for (int r = 0; r < 4; ++r) {
            int gm = bm + wr + m * 16 + cr + r;
            if (gm < M)
              ((__hip_bfloat16*)Cout)[(size_t)gm * 512 + col] = __float2bfloat16(acc[m][n][r]);
          }
        }
      }
      float asv[4], adv[4];
#pragma unroll
      for (int n = 0; n < 4; ++n) {
        int ch = bn + wc + n * 16 + cc;
        asv[n] = asrc[ch]; adv[n] = adst[ch];
      }
      float* spal = (float*)As0;
      float* spar = spal + 256;
#pragma unroll
      for (int m = 0; m < 4; ++m) {
#pragma unroll
        for (int r = 0; r < 4; ++r) {
          float pa = acc[m][0][r] * asv[0] + acc[m][1][r] * asv[1]
                   + acc[m][2][r] * asv[2] + acc[m][3][r] * asv[3];
          float pb = acc[m][0][r] * adv[0] + acc[m][1][r] * adv[1]
                   + acc[m][2][r] * adv[2] + acc[m][3][r] * adv[3];
#pragma unroll
          for (int o = 1; o < 16; o <<= 1) {
            pa += __shfl_xor(pa, o);
            pb += __shfl_xor(pb, o);
          }
          if (cc == 0) {
            int rl = m * 16 + cr + r;
            spal[w * 64 + rl] = pa;
            spar[w * 64 + rl] = pb;
          }
        }
      }
      __syncthreads();
      if ((w & 1) == 0) {
        float av = spal[w * 64 + l] + spal[(w + 1) * 64 + l];
        float rv = spar[w * 64 + l] + spar[(w + 1) * 64 + l];
        int row = bm + wr + l;
        if (row < Nn) { al[row * 4 + cb] = av; ar[row * 4 + cb] = rv; }
      }
    } else {
#pragma unroll
      for (int n = 0; n < 4; ++n) {
        int col2 = wc + n * 16 + cc;
        float bb = bias2[col2];
#pragma unroll
        for (int m = 0; m < 4; ++m) {
#pragma unroll
          for (int r = 0; r < 4; ++r) {
            int gm = bm + wr + m * 16 + cr + r;
            if (gm < Nn) C2[(size_t)gm * 128 + col2] = acc[m][n][r] + bb;
          }
        }
      }
    }
  }

  if (EPI == 2) {
    float bb[4], gl_[4], gb_[4];
#pragma unroll
    for (int n = 0; n < 4; ++n) {
      int col = wc + n * 16 + cc;
      bb[n] = bias[col]; gl_[n] = lng[col]; gb_[n] = lnb[col];
    }
    float* ssum = (float*)As0;
    float* ssq = ssum + 256;
    float* smu = ssum + 512;
    float* srs = ssum + 640;
#pragma unroll
    for (int m = 0; m < 4; ++m) {
#pragma unroll
      for (int r = 0; r < 4; ++r) {
        float s = 0.f, q = 0.f;
#pragma unroll
        for (int n = 0; n < 4; ++n) {
          float z = acc[m][n][r] + bb[n];
          s += z; q += z * z;
        }
#pragma unroll
        for (int o = 1; o < 16; o <<= 1) {
          s += __shfl_xor(s, o);
          q += __shfl_xor(q, o);
        }
        if (cc == 0) {
          int rl = m * 16 + cr + r;
          ssum[w * 64 + rl] = s;
          ssq[w * 64 + rl] = q;
        }
      }
    }
    __syncthreads();
    if ((w & 1) == 0) {
      float s = ssum[w * 64 + l] + ssum[(w + 1) * 64 + l];
      float q = ssq[w * 64 + l] + ssq[(w + 1) * 64 + l];
      float mu = s * (1.f / 128.f);
      float var = q * (1.f / 128.f) - mu * mu;
      smu[wr + l] = mu;
      srs[wr + l] = rsqrtf(var + 1e-5f);
    }
    __syncthreads();
#pragma unroll
    for (int m = 0; m < 4; ++m) {
#pragma unroll
      for (int r = 0; r < 4; ++r) {
        int rl = wr + m * 16 + cr + r;
        int gm = bm + rl;
        if (gm < M) {
          float mu = smu[rl], rs = srs[rl];
#pragma unroll
          for (int n = 0; n < 4; ++n) {
            int col = wc + n * 16 + cc;
            float z = acc[m][n][r] + bb[n];
            float y = (z - mu) * rs * gl_[n] + gb_[n] + resid[(size_t)gm * 128 + col];
            resid[(size_t)gm * 128 + col] = y;
          }
        }
      }
    }
  }
}

// ---------------- GAT aggregation: wave per dst node, 4-deep gather pipeline ----------------
__global__ __launch_bounds__(256) void k_gat_agg(
    const __hip_bfloat16* __restrict__ xl, const float* __restrict__ al,
    const float* __restrict__ ar, const int* __restrict__ off,
    const int* __restrict__ lst, const float* __restrict__ bias,
    __hip_bfloat16* __restrict__ outb, __hip_bfloat16* __restrict__ outh,
    int mode, int N)
{
  __shared__ int   sside[4][64];
  __shared__ float sebuf[4][4][68];
  int w = threadIdx.x >> 6, l = threadIdx.x & 63;
  int d = blockIdx.x * 4 + w;
  bool active = (d < N);
  int base = 0, deg = 0, tot = 0;
  float4 arv = make_float4(0.f, 0.f, 0.f, 0.f);
  if (active) {
    base = off[d]; deg = off[d + 1] - base; tot = deg + 1;
    arv = *(const float4*)(ar + 4 * d);
  }
  int hh = l >> 4;
  float facc[8] = {0.f, 0.f, 0.f, 0.f, 0.f, 0.f, 0.f, 0.f};
  float dn0 = 0.f, dn1 = 0.f, dn2 = 0.f, dn3 = 0.f;
  const uint4* xw = (const uint4*)xl;
  auto fma8 = [&](uint4 pv, float e) {
    facc[0] += e * __uint_as_float(pv.x << 16);
    facc[1] += e * __uint_as_float(pv.x & 0xffff0000u);
    facc[2] += e * __uint_as_float(pv.y << 16);
    facc[3] += e * __uint_as_float(pv.y & 0xffff0000u);
    facc[4] += e * __uint_as_float(pv.z << 16);
    facc[5] += e * __uint_as_float(pv.z & 0xffff0000u);
    facc[6] += e * __uint_as_float(pv.w << 16);
    facc[7] += e * __uint_as_float(pv.w & 0xffff0000u);
  };
  for (int cb = 0; cb < tot; cb += 64) {
    int j = cb + l;
    float e0 = 0.f, e1 = 0.f, e2 = 0.f, e3 = 0.f;
    int sid = 0;
    if (j < tot) {
      sid = (j == deg) ? d : lst[base + j];
      float4 av = *(const float4*)(al + 4 * sid);
      e0 = __expf(lrelu(av.x + arv.x));
      e1 = __expf(lrelu(av.y + arv.y));
      e2 = __expf(lrelu(av.z + arv.z));
      e3 = __expf(lrelu(av.w + arv.w));
      dn0 += e0; dn1 += e1; dn2 += e2; dn3 += e3;
    }
    sside[w][l] = sid;
    sebuf[w][0][l] = e0; sebuf[w][1][l] = e1;
    sebuf[w][2][l] = e2; sebuf[w][3][l] = e3;
    int cnt = tot - cb; if (cnt > 64) cnt = 64;
    int jj = 0;
    for (; jj + 4 <= cnt; jj += 4) {
      int s0 = sside[w][jj], s1 = sside[w][jj + 1];
      int s2 = sside[w][jj + 2], s3 = sside[w][jj + 3];
      float ea = sebuf[w][hh][jj], eb = sebuf[w][hh][jj + 1];
      float ec = sebuf[w][hh][jj + 2], ed = sebuf[w][hh][jj + 3];
      uint4 p0 = xw[(size_t)s0 * 64 + l];
      uint4 p1 = xw[(size_t)s1 * 64 + l];
      uint4 p2 = xw[(size_t)s2 * 64 + l];
      uint4 p3 = xw[(size_t)s3 * 64 + l];
      fma8(p0, ea); fma8(p1, eb); fma8(p2, ec); fma8(p3, ed);
    }
    for (; jj < cnt; ++jj) {
      int s0 = sside[w][jj];
      float ea = sebuf[w][hh][jj];
      uint4 p0 = xw[(size_t)s0 * 64 + l];
      fma8(p0, ea);
    }
  }
#pragma unroll
  for (int o = 1; o < 64; o <<= 1) {
    dn0 += __shfl_xor(dn0, o); dn1 += __shfl_xor(dn1, o);
    dn2 += __shfl_xor(dn2, o); dn3 += __shfl_xor(dn3, o);
  }
  if (!active) return;
  float dsel = hh == 0 ? dn0 : hh == 1 ? dn1 : hh == 2 ? dn2 : dn3;
  float rden = 1.f / dsel;
  if (mode == 0) {
    int c8 = l * 8;
    const float4* bp = (const float4*)(bias + c8);
    float4 b0 = bp[0], b1 = bp[1];
    float vb[8] = {b0.x, b0.y, b0.z, b0.w, b1.x, b1.y, b1.z, b1.w};
    uint4 o4; uint* po = (uint*)&o4;
#pragma unroll
    for (int i = 0; i < 4; ++i) {
      float v0 = fmaxf(facc[2*i]   * rden + vb[2*i],   0.f);
      float v1 = fmaxf(facc[2*i+1] * rden + vb[2*i+1], 0.f);
      po[i] = packbf(v0, v1);
    }
    ((uint4*)outb)[(size_t)d * 64 + l] = o4;
  } else {
#pragma unroll
    for (int i = 0; i < 8; ++i) {
      facc[i] *= rden;
      facc[i] += __shfl_xor(facc[i], 16);
      facc[i] += __shfl_xor(facc[i], 32);
    }
    if (l < 16) {
      int c = l * 8;
      const float4* bp = (const float4*)(bias + c);
      float4 b0 = bp[0], b1 = bp[1];
      float vb[8] = {b0.x, b0.y, b0.z, b0.w, b1.x, b1.y, b1.z, b1.w};
      uint4 o4; uint* po = (uint*)&o4;
#pragma unroll
      for (int i = 0; i < 4; ++i) {
        float v0 = fmaxf(facc[2*i]   * 0.25f + vb[2*i],   0.f);
        float v1 = fmaxf(facc[2*i+1] * 0.25f + vb[2*i+1], 0.f);
        po[i] = packbf(v0, v1);
      }
      ((uint4*)outh)[(size_t)d * 16 + l] = o4;
    }
  }
}

// ---------------- final src-side segment sum (h3 bf16 -> aggbf bf16), 4-deep ----------------
__global__ __launch_bounds__(256) void k_aggsrc(const __hip_bfloat16* __restrict__ h3,
    const int* __restrict__ off, const int* __restrict__ lst,
    __hip_bfloat16* __restrict__ out, int N) {
  int w = threadIdx.x >> 6, l = threadIdx.x & 63;
  int n = blockIdx.x * 4 + w;
  if (n >= N) return;
  const uint* hw = (const uint*)h3;
  uint pv = hw[(size_t)n * 64 + l];
  float a0 = __uint_as_float(pv << 16);
  float a1 = __uint_as_float(pv & 0xffff0000u);
  float b0 = 0.f, b1 = 0.f, c0 = 0.f, c1 = 0.f, d0 = 0.f, d1 = 0.f;
  int b = off[n], e = off[n + 1];
  int j = b;
  for (; j + 4 <= e; j += 4) {
    int s0 = lst[j], s1 = lst[j + 1], s2 = lst[j + 2], s3 = lst[j + 3];
    uint q0 = hw[(size_t)s0 * 64 + l];
    uint q1 = hw[(size_t)s1 * 64 + l];
    uint q2 = hw[(size_t)s2 * 64 + l];
    uint q3 = hw[(size_t)s3 * 64 + l];
    a0 += __uint_as_float(q0 << 16); a1 += __uint_as_float(q0 & 0xffff0000u);
    b0 += __uint_as_float(q1 << 16); b1 += __uint_as_float(q1 & 0xffff0000u);
    c0 += __uint_as_float(q2 << 16); c1 += __uint_as_float(q2 & 0xffff0000u);
    d0 += __uint_as_float(q3 << 16); d1 += __uint_as_float(q3 & 0xffff0000u);
  }
  for (; j < e; ++j) {
    uint q = hw[(size_t)lst[j] * 64 + l];
    a0 += __uint_as_float(q << 16);
    a1 += __uint_as_float(q & 0xffff0000u);
  }
  ((uint*)out)[(size_t)n * 64 + l] = packbf((a0 + b0) + (c0 + d0), (a1 + b1) + (c1 + d1));
}

extern "C" void kernel_launch(void* const* d_in, const int* in_sizes, int n_in,
                              void* d_out, int out_size, void* d_ws, size_t ws_size,
                              hipStream_t stream) {
  (void)n_in; (void)out_size; (void)ws_size;
  const float* x   = (const float*)d_in[0];
  const float* et  = (const float*)d_in[1];
  const float* W1  = (const float*)d_in[2];
  const float* as1 = (const float*)d_in[3];
  const float* ad1 = (const float*)d_in[4];
  const float* b1  = (const float*)d_in[5];
  const float* W2  = (const float*)d_in[6];
  const float* as2 = (const float*)d_in[7];
  const float* ad2 = (const float*)d_in[8];
  const float* b2  = (const float*)d_in[9];
  const float* W3  = (const float*)d_in[10];
  const float* as3 = (const float*)d_in[11];
  const float* ad3 = (const float*)d_in[12];
  const float* b3  = (const float*)d_in[13];
  const float* tW1 = (const float*)d_in[14];
  const float* tb1 = (const float*)d_in[15];
  const float* tW2 = (const float*)d_in[16];
  const float* tb2 = (const float*)d_in[17];
  const float* fW1 = (const float*)d_in[18];
  const float* fb1 = (const float*)d_in[19];
  const float* fW2 = (const float*)d_in[20];
  const float* fb2 = (const float*)d_in[21];
  const float* lng = (const float*)d_in[22];
  const float* lnb = (const float*)d_in[23];
  const float* rW  = (const float*)d_in[24];
  const float* rb  = (const float*)d_in[25];
  const int*   ei  = (const int*)d_in[26];
  const int N = in_sizes[0] / 64;     // 20000
  const int E = in_sizes[26] / 2;     // 320000
  const int Mp = ((N + 127) / 128) * 128;  // 20096
  const int* src = ei;
  const int* dst = ei + E;

  char* cur = (char*)d_ws;
  auto carve = [&](size_t bytes) { char* p = cur; cur += (bytes + 255) & ~(size_t)255; return p; };
  __hip_bfloat16* xbf  = (__hip_bfloat16*)carve((size_t)Mp * 64 * 2);
  __hip_bfloat16* habf = (__hip_bfloat16*)carve((size_t)Mp * 512 * 2);
  __hip_bfloat16* xlbf = (__hip_bfloat16*)carve((size_t)Mp * 512 * 2);
  __hip_bfloat16* wtCat= (__hip_bfloat16*)carve((size_t)640 * 64 * 2);  // [W1t(512); rWt(128)]
  __hip_bfloat16* wt2  = (__hip_bfloat16*)carve((size_t)512 * 512 * 2);
  __hip_bfloat16* wt3  = (__hip_bfloat16*)carve((size_t)512 * 512 * 2);
  __hip_bfloat16* wtF1 = (__hip_bfloat16*)carve((size_t)128 * 128 * 2);
  __hip_bfloat16* wtF2 = (__hip_bfloat16*)carve((size_t)128 * 128 * 2);
  __hip_bfloat16* aggbf= (__hip_bfloat16*)carve((size_t)Mp * 128 * 2);
  __hip_bfloat16* z1bf = (__hip_bfloat16*)carve((size_t)Mp * 128 * 2);
  __hip_bfloat16* h3   = (__hip_bfloat16*)carve((size_t)N * 128 * 2);
  float* al   = (float*)carve((size_t)N * 4 * 4);
  float* ar   = (float*)carve((size_t)N * 4 * 4);
  float* cvec = (float*)carve(128 * 4);
  int* offD = (int*)carve((size_t)(N + 1) * 4);
  int* offS = (int*)carve((size_t)(N + 1) * 4);
  int* lstD = (int*)carve((size_t)E * 4);
  int* lstS = (int*)carve((size_t)E * 4);
  char* zstart = cur;
  int* cntD = (int*)carve((size_t)N * 4);
  int* curD = (int*)carve((size_t)N * 4);
  int* cntS = (int*)carve((size_t)N * 4);
  int* curS = (int*)carve((size_t)N * 4);
  float* tacc = (float*)carve(64 * 4);
  size_t zbytes = (size_t)(cur - zstart);
  float* xres = (float*)d_out;

  hipMemsetAsync(zstart, 0, zbytes, stream);

  // CSR build + time path (fused)
  k_countT<<<(E + 255) / 256, 256, 0, stream>>>(src, dst, E, cntD, cntS, et, tW1, tb1, tacc);
  k_scan2c<<<3, 1024, 0, stream>>>(cntD, offD, cntS, offS, N, tacc, tW2, tb2, fW1, fb1, cvec, E);
  k_fill<<<(E + 255) / 256, 256, 0, stream>>>(src, dst, E, offD, curD, lstD, offS, curS, lstS);

  // fused prep: weight transposes + x conversion + pad zero
  {
    PrepArgs pa;
    int ts = 0;
    auto setd = [&](int i, const float* W, __hip_bfloat16* Wt, int K, int Nw) {
      pa.W[i] = W; pa.Wt[i] = Wt; pa.K[i] = K; pa.Nw[i] = Nw; pa.tstart[i] = ts;
      ts += (K / 32) * (Nw / 64);
    };
    setd(0, W1, wtCat, 64, 512);
    setd(1, W2, wt2, 512, 512);
    setd(2, W3, wt3, 512, 512);
    setd(3, rW, wtCat + (size_t)512 * 64, 64, 128);
    setd(4, fW1, wtF1, 128, 128);
    setd(5, fW2, wtF2, 128, 128);
    pa.NC = ts;
    pa.XB = Mp / 16;
    int grid = pa.NC + pa.XB + (Mp - N);
    k_prep<<<grid, 256, 0, stream>>>(pa, x, xbf, habf, aggbf, N, Mp);
  }

  const int TB = Mp / 128;  // 157
  const int GB = (N + 3) / 4;

  // layer 1 fused with x_res
  gemm_t<1><<<dim3(TB, 5), 256, 0, stream>>>(xbf, wtCat, xlbf, nullptr, Mp, 640, 64, 0, N,
      as1, ad1, al, ar, xres, rb, nullptr, nullptr, nullptr);
  k_gat_agg<<<GB, 256, 0, stream>>>(xlbf, al, ar, offD, lstD, b1, habf, nullptr, 0, N);
  // layer 2
  gemm_t<1><<<dim3(TB, 4), 256, 0, stream>>>(habf, wt2, xlbf, nullptr, Mp, 512, 512, 0, N,
      as2, ad2, al, ar, nullptr, nullptr, nullptr, nullptr, nullptr);
  k_gat_agg<<<GB, 256, 0, stream>>>(xlbf, al, ar, offD, lstD, b2, habf, nullptr, 0, N);
  // layer 3 (head-mean epilogue -> h3 bf16)
  gemm_t<1><<<dim3(TB, 4), 256, 0, stream>>>(habf, wt3, xlbf, nullptr, Mp, 512, 512, 0, N,
      as3, ad3, al, ar, nullptr, nullptr, nullptr, nullptr, nullptr);
  k_gat_agg<<<GB, 256, 0, stream>>>(xlbf, al, ar, offD, lstD, b3, nullptr, h3, 1, N);

  // agg = segment_sum(h3[dst], src) -> bf16
  k_aggsrc<<<GB, 256, 0, stream>>>(h3, offS, lstS, aggbf, N);

  // z1 = relu(agg @ fW1[:128] + cvec) (bf16)
  gemm_t<0><<<dim3(TB, 1), 256, 0, stream>>>(aggbf, wtF1, z1bf, cvec, Mp, 128, 128, 1, N,
      nullptr, nullptr, nullptr, nullptr, nullptr, nullptr, nullptr, nullptr, nullptr);
  // z2 = z1 @ fW2 + fb2, fused LN + residual -> d_out
  gemm_t<2><<<dim3(TB, 1), 256, 0, stream>>>(z1bf, wtF2, nullptr, fb2, N, 128, 128, 0, N,
      nullptr, nullptr, nullptr, nullptr, nullptr, nullptr, lng, lnb, xres);
}